// Round 1
// baseline (1034.483 us; speedup 1.0000x reference)
//
#include <hip/hip_runtime.h>

#define NN 50000
#define NE 800000
#define NG 512
#define FIN 128
#define HID 256

static inline int cdiv(int a, int b) { return (a + b - 1) / b; }

// ---- histogram (also used for batch counts) ----
__global__ void count_kernel(const int* __restrict__ idx, int* __restrict__ cnt, int n) {
    int i = blockIdx.x * 256 + threadIdx.x;
    if (i < n) atomicAdd(&cnt[idx[i]], 1);
}

// dis[i] = rsqrt(in_degree + 1 self loop)
__global__ void dis_kernel(const int* __restrict__ cnt, float* __restrict__ dis, int n) {
    int i = blockIdx.x * 256 + threadIdx.x;
    if (i < n) dis[i] = rsqrtf((float)cnt[i] + 1.0f);
}

// exclusive scan over n ints, single block of 256 threads; out has n+1 entries
__global__ void scan_kernel(const int* __restrict__ in, int* __restrict__ out, int n) {
    __shared__ int wsum[4];
    __shared__ int carry_s;
    int tid = threadIdx.x, lane = tid & 63, wid = tid >> 6;
    if (tid == 0) carry_s = 0;
    __syncthreads();
    for (int base = 0; base < n; base += 256) {
        int i = base + tid;
        int v = (i < n) ? in[i] : 0;
        int incl = v;
        #pragma unroll
        for (int off = 1; off < 64; off <<= 1) {
            int u = __shfl_up(incl, off, 64);
            if (lane >= off) incl += u;
        }
        if (lane == 63) wsum[wid] = incl;
        __syncthreads();
        int woff = 0;
        for (int w = 0; w < wid; ++w) woff += wsum[w];
        int total = wsum[0] + wsum[1] + wsum[2] + wsum[3];
        if (i < n) out[i] = carry_s + woff + incl - v;
        __syncthreads();
        if (tid == 0) carry_s += total;
        __syncthreads();
    }
    if (threadIdx.x == 0) out[n] = carry_s;
}

__global__ void fill_kernel(const int* __restrict__ src, const int* __restrict__ dst,
                            int* __restrict__ cursor, int* __restrict__ col, int n) {
    int i = blockIdx.x * 256 + threadIdx.x;
    if (i < n) {
        int pos = atomicAdd(&cursor[dst[i]], 1);
        col[pos] = src[i];
    }
}

// Y[i,:] = dis[i] * (A[i,:] @ B)   A:[M,K] B:[K,256] Y:[M,256]
__global__ __launch_bounds__(256) void gemm_scale_kernel(
        const float* __restrict__ A, const float* __restrict__ B,
        const float* __restrict__ dis, float* __restrict__ Y, int M, int K) {
    __shared__ float As[16][68];   // [k][m], stride 68 keeps float4 alignment
    __shared__ float Bs[16][64];   // [k][n]
    const int bm = blockIdx.x * 64, bn = blockIdx.y * 64;
    const int tid = threadIdx.x;
    const int tx = tid & 15, ty = tid >> 4;
    const int ar = tid >> 2, akc = (tid & 3) * 4;   // A-load: row, k-col
    const int bkr = tid >> 4, bnc = (tid & 15) * 4; // B-load: k-row, n-col
    const int arow = bm + ar;
    float acc[4][4] = {};
    for (int k0 = 0; k0 < K; k0 += 16) {
        float4 a = make_float4(0.f, 0.f, 0.f, 0.f);
        if (arow < M) a = *(const float4*)(A + (size_t)arow * K + k0 + akc);
        As[akc + 0][ar] = a.x; As[akc + 1][ar] = a.y;
        As[akc + 2][ar] = a.z; As[akc + 3][ar] = a.w;
        *(float4*)&Bs[bkr][bnc] = *(const float4*)(B + (size_t)(k0 + bkr) * HID + bn + bnc);
        __syncthreads();
        #pragma unroll
        for (int k = 0; k < 16; ++k) {
            float4 av = *(const float4*)&As[k][ty * 4];
            float4 bv = *(const float4*)&Bs[k][tx * 4];
            acc[0][0] += av.x * bv.x; acc[0][1] += av.x * bv.y; acc[0][2] += av.x * bv.z; acc[0][3] += av.x * bv.w;
            acc[1][0] += av.y * bv.x; acc[1][1] += av.y * bv.y; acc[1][2] += av.y * bv.z; acc[1][3] += av.y * bv.w;
            acc[2][0] += av.z * bv.x; acc[2][1] += av.z * bv.y; acc[2][2] += av.z * bv.z; acc[2][3] += av.z * bv.w;
            acc[3][0] += av.w * bv.x; acc[3][1] += av.w * bv.y; acc[3][2] += av.w * bv.z; acc[3][3] += av.w * bv.w;
        }
        __syncthreads();
    }
    #pragma unroll
    for (int i = 0; i < 4; ++i) {
        int row = bm + ty * 4 + i;
        if (row < M) {
            float dv = dis[row];
            float4 o = make_float4(dv * acc[i][0], dv * acc[i][1], dv * acc[i][2], dv * acc[i][3]);
            *(float4*)(Y + (size_t)row * HID + bn + tx * 4) = o;
        }
    }
}

// one wave per node: H[v,:] = relu(dis[v]*(sum_{u in N(v)} Y[u,:] + Y[v,:]) + b)
__global__ __launch_bounds__(256) void agg_kernel(
        const float* __restrict__ Y, const int* __restrict__ row_ptr,
        const int* __restrict__ col, const float* __restrict__ dis,
        const float* __restrict__ bias, float* __restrict__ H, int n) {
    int node = blockIdx.x * 4 + (threadIdx.x >> 6);
    if (node >= n) return;
    int lane = threadIdx.x & 63;
    const float4* Yv = (const float4*)Y;
    float4 acc = Yv[(size_t)node * 64 + lane];  // self loop
    int e = row_ptr[node], end = row_ptr[node + 1];
    for (; e + 1 < end; e += 2) {
        int u0 = col[e], u1 = col[e + 1];
        float4 m0 = Yv[(size_t)u0 * 64 + lane];
        float4 m1 = Yv[(size_t)u1 * 64 + lane];
        acc.x += m0.x + m1.x; acc.y += m0.y + m1.y;
        acc.z += m0.z + m1.z; acc.w += m0.w + m1.w;
    }
    if (e < end) {
        int u = col[e];
        float4 m = Yv[(size_t)u * 64 + lane];
        acc.x += m.x; acc.y += m.y; acc.z += m.z; acc.w += m.w;
    }
    float dv = dis[node];
    float4 b = ((const float4*)bias)[lane];
    float4 o;
    o.x = fmaxf(fmaf(dv, acc.x, b.x), 0.f);
    o.y = fmaxf(fmaf(dv, acc.y, b.y), 0.f);
    o.z = fmaxf(fmaf(dv, acc.z, b.z), 0.f);
    o.w = fmaxf(fmaf(dv, acc.w, b.w), 0.f);
    ((float4*)H)[(size_t)node * 64 + lane] = o;
}

// one block per graph: mean-pool + concat + FC1(relu) + FC2
__global__ __launch_bounds__(256) void pool_mlp_kernel(
        const float* __restrict__ H, const int* __restrict__ goff,
        const float* __restrict__ mol, const float* __restrict__ rings,
        const float* __restrict__ fcW1, const float* __restrict__ fcb1,
        const float* __restrict__ fcW2, const float* __restrict__ fcb2,
        float* __restrict__ out) {
    __shared__ float s_hg[258];
    __shared__ float s_t[196];
    int g = blockIdx.x, tid = threadIdx.x;
    int beg = goff[g], end = goff[g + 1];
    float acc = 0.f;
    for (int i = beg; i < end; ++i) acc += H[(size_t)i * HID + tid];
    s_hg[tid] = acc / fmaxf((float)(end - beg), 1.0f);
    if (tid == 0) { s_hg[256] = mol[g]; s_hg[257] = rings[g]; }
    __syncthreads();
    if (tid < 196) {
        float a = fcb1[tid];
        for (int k = 0; k < 258; ++k) a = fmaf(s_hg[k], fcW1[k * 196 + tid], a);
        s_t[tid] = fmaxf(a, 0.f);
    }
    __syncthreads();
    if (tid < 16) {
        float a = fcb2[tid];
        for (int k = 0; k < 196; ++k) a = fmaf(s_t[k], fcW2[k * 16 + tid], a);
        out[g * 16 + tid] = a;
    }
}

extern "C" void kernel_launch(void* const* d_in, const int* in_sizes, int n_in,
                              void* d_out, int out_size, void* d_ws, size_t ws_size,
                              hipStream_t stream) {
    const float* x     = (const float*)d_in[0];
    const int*   ei    = (const int*)d_in[1];
    const int*   batch = (const int*)d_in[2];
    const float* mol   = (const float*)d_in[3];
    const float* rings = (const float*)d_in[4];
    const float* W1 = (const float*)d_in[5];
    const float* b1 = (const float*)d_in[6];
    const float* W2 = (const float*)d_in[7];
    const float* b2 = (const float*)d_in[8];
    const float* W3 = (const float*)d_in[9];
    const float* b3 = (const float*)d_in[10];
    const float* fcW1 = (const float*)d_in[11];
    const float* fcb1 = (const float*)d_in[12];
    const float* fcW2 = (const float*)d_in[13];
    const float* fcb2 = (const float*)d_in[14];
    float* out = (float*)d_out;
    const int* src = ei;
    const int* dst = ei + NE;

    char* w = (char*)d_ws;
    auto alloc = [&](size_t bytes) {
        char* p = w;
        w += (bytes + 255) & ~(size_t)255;
        return p;
    };
    int*   cnt     = (int*)alloc((size_t)NN * 4);
    int*   row_ptr = (int*)alloc((size_t)(NN + 1) * 4);
    int*   cursor  = (int*)alloc((size_t)NN * 4);
    int*   gcnt    = (int*)alloc((size_t)NG * 4);
    int*   goff    = (int*)alloc((size_t)(NG + 1) * 4);
    float* dis     = (float*)alloc((size_t)NN * 4);
    int*   col     = (int*)alloc((size_t)NE * 4);
    float* Y       = (float*)alloc((size_t)NN * HID * 4);
    float* H       = (float*)alloc((size_t)NN * HID * 4);

    hipMemsetAsync(cnt, 0, (size_t)NN * 4, stream);
    hipMemsetAsync(gcnt, 0, (size_t)NG * 4, stream);
    count_kernel<<<cdiv(NE, 256), 256, 0, stream>>>(dst, cnt, NE);
    count_kernel<<<cdiv(NN, 256), 256, 0, stream>>>(batch, gcnt, NN);
    dis_kernel<<<cdiv(NN, 256), 256, 0, stream>>>(cnt, dis, NN);
    scan_kernel<<<1, 256, 0, stream>>>(cnt, row_ptr, NN);
    scan_kernel<<<1, 256, 0, stream>>>(gcnt, goff, NG);
    hipMemcpyAsync(cursor, row_ptr, (size_t)NN * 4, hipMemcpyDeviceToDevice, stream);
    fill_kernel<<<cdiv(NE, 256), 256, 0, stream>>>(src, dst, cursor, col, NE);

    dim3 ggrid(cdiv(NN, 64), 4);
    int agrid = cdiv(NN, 4);
    gemm_scale_kernel<<<ggrid, 256, 0, stream>>>(x, W1, dis, Y, NN, FIN);
    agg_kernel<<<agrid, 256, 0, stream>>>(Y, row_ptr, col, dis, b1, H, NN);
    gemm_scale_kernel<<<ggrid, 256, 0, stream>>>(H, W2, dis, Y, NN, HID);
    agg_kernel<<<agrid, 256, 0, stream>>>(Y, row_ptr, col, dis, b2, H, NN);
    gemm_scale_kernel<<<ggrid, 256, 0, stream>>>(H, W3, dis, Y, NN, HID);
    agg_kernel<<<agrid, 256, 0, stream>>>(Y, row_ptr, col, dis, b3, H, NN);
    pool_mlp_kernel<<<NG, 256, 0, stream>>>(H, goff, mol, rings, fcW1, fcb1, fcW2, fcb2, out);
}

// Round 2
// 685.738 us; speedup vs baseline: 1.5086x; 1.5086x over previous
//
#include <hip/hip_runtime.h>

#define NN 50000
#define NE 800000
#define NG 512
#define FIN 128
#define HID 256

typedef short short8 __attribute__((ext_vector_type(8)));
typedef float f32x4 __attribute__((ext_vector_type(4)));

static inline int cdiv(int a, int b) { return (a + b - 1) / b; }

static __device__ inline unsigned short f2bf(float f) {
    unsigned int u = __float_as_uint(f);
    unsigned int r = (u + 0x7FFF + ((u >> 16) & 1)) >> 16;  // RNE
    return (unsigned short)r;
}
static __device__ inline float bf2f(unsigned short h) {
    return __uint_as_float(((unsigned int)h) << 16);
}

// ---- histogram (also used for batch counts) ----
__global__ void count_kernel(const int* __restrict__ idx, int* __restrict__ cnt, int n) {
    int i = blockIdx.x * 256 + threadIdx.x;
    if (i < n) atomicAdd(&cnt[idx[i]], 1);
}

__global__ void dis_kernel(const int* __restrict__ cnt, float* __restrict__ dis, int n) {
    int i = blockIdx.x * 256 + threadIdx.x;
    if (i < n) dis[i] = rsqrtf((float)cnt[i] + 1.0f);
}

// single-block exclusive scan (small n only: NG=512, block partials=196)
__global__ void scan_kernel(const int* __restrict__ in, int* __restrict__ out, int n) {
    __shared__ int wsum[4];
    __shared__ int carry_s;
    int tid = threadIdx.x, lane = tid & 63, wid = tid >> 6;
    if (tid == 0) carry_s = 0;
    __syncthreads();
    for (int base = 0; base < n; base += 256) {
        int i = base + tid;
        int v = (i < n) ? in[i] : 0;
        int incl = v;
        #pragma unroll
        for (int off = 1; off < 64; off <<= 1) {
            int u = __shfl_up(incl, off, 64);
            if (lane >= off) incl += u;
        }
        if (lane == 63) wsum[wid] = incl;
        __syncthreads();
        int woff = 0;
        for (int w = 0; w < wid; ++w) woff += wsum[w];
        int total = wsum[0] + wsum[1] + wsum[2] + wsum[3];
        if (i < n) out[i] = carry_s + woff + incl - v;
        __syncthreads();
        if (tid == 0) carry_s += total;
        __syncthreads();
    }
    if (threadIdx.x == 0) out[n] = carry_s;
}

// hierarchical scan pass 1: per-block sum of 256 ints
__global__ void block_reduce_kernel(const int* __restrict__ in, int* __restrict__ bsum, int n) {
    int i = blockIdx.x * 256 + threadIdx.x;
    int v = (i < n) ? in[i] : 0;
    #pragma unroll
    for (int off = 32; off; off >>= 1) v += __shfl_down(v, off, 64);
    __shared__ int ws[4];
    if ((threadIdx.x & 63) == 0) ws[threadIdx.x >> 6] = v;
    __syncthreads();
    if (threadIdx.x == 0) bsum[blockIdx.x] = ws[0] + ws[1] + ws[2] + ws[3];
}

// hierarchical scan pass 3: local exclusive scan + block offset
__global__ void scan_add_kernel(const int* __restrict__ in, const int* __restrict__ boff,
                                int* __restrict__ out, int n) {
    int b = blockIdx.x, tid = threadIdx.x;
    int i = b * 256 + tid;
    int lane = tid & 63, wid = tid >> 6;
    int v = (i < n) ? in[i] : 0;
    int incl = v;
    #pragma unroll
    for (int off = 1; off < 64; off <<= 1) {
        int u = __shfl_up(incl, off, 64);
        if (lane >= off) incl += u;
    }
    __shared__ int ws[4];
    if (lane == 63) ws[wid] = incl;
    __syncthreads();
    int woff = 0;
    for (int w = 0; w < wid; ++w) woff += ws[w];
    if (i < n) out[i] = boff[b] + woff + incl - v;
    if (b == 0 && tid == 0) out[n] = boff[gridDim.x];
}

__global__ void fill_kernel(const int* __restrict__ src, const int* __restrict__ dst,
                            int* __restrict__ cursor, int* __restrict__ col, int n) {
    int i = blockIdx.x * 256 + threadIdx.x;
    if (i < n) {
        int pos = atomicAdd(&cursor[dst[i]], 1);
        col[pos] = src[i];
    }
}

// cast fp32 -> bf16, vectorized
__global__ void cast_bf16_kernel(const float* __restrict__ in, unsigned short* __restrict__ out, int n4) {
    int i = blockIdx.x * 256 + threadIdx.x;
    if (i < n4) {
        float4 v = ((const float4*)in)[i];
        ushort4 o;
        o.x = f2bf(v.x); o.y = f2bf(v.y); o.z = f2bf(v.z); o.w = f2bf(v.w);
        ((ushort4*)out)[i] = o;
    }
}

// W [K,256] fp32 -> Wt [256,K] bf16
__global__ void tcast_kernel(const float* __restrict__ W, unsigned short* __restrict__ Wt, int K) {
    int idx = blockIdx.x * 256 + threadIdx.x;
    int total = K * 256;
    if (idx < total) {
        int n = idx / K, k = idx - n * K;
        Wt[idx] = f2bf(W[(size_t)k * 256 + n]);
    }
}

// Y[i,:] = dis[i] * (A[i,:] @ B)   A:[M,K] bf16, Bt:[256,K] bf16 (pre-transposed), Y:[M,256] fp32
// block: 256 thr = 4 waves; tile 64(M) x 64(N); BK=32; wave w -> rows 16w..16w+15, all 64 N
__global__ __launch_bounds__(256) void gemm_bf16_kernel(
        const unsigned short* __restrict__ A, const unsigned short* __restrict__ Bt,
        const float* __restrict__ dis, float* __restrict__ Y, int M, int K) {
    #define LDT 40  // padded k-stride (bf16 elems); 80B keeps 16B alignment
    __shared__ unsigned short As[64][LDT];
    __shared__ unsigned short Bs[64][LDT];
    const int tid = threadIdx.x;
    const int bm = blockIdx.x * 64, bn = blockIdx.y * 64;
    const int wave = tid >> 6, lane = tid & 63;
    const int l16 = lane & 15, quad = lane >> 4;
    const int lr = tid >> 2, lc = (tid & 3) * 8;  // staging: row, k-offset (uint4 = 8 bf16)

    f32x4 acc[4];
    #pragma unroll
    for (int i = 0; i < 4; ++i) acc[i] = (f32x4){0.f, 0.f, 0.f, 0.f};

    const int arow = bm + lr;
    for (int k0 = 0; k0 < K; k0 += 32) {
        uint4 av = make_uint4(0, 0, 0, 0);
        if (arow < M) av = *(const uint4*)(A + (size_t)arow * K + k0 + lc);
        *(uint4*)&As[lr][lc] = av;
        uint4 bv = *(const uint4*)(Bt + (size_t)(bn + lr) * K + k0 + lc);
        *(uint4*)&Bs[lr][lc] = bv;
        __syncthreads();
        short8 af = *(const short8*)&As[wave * 16 + l16][quad * 8];
        #pragma unroll
        for (int nt = 0; nt < 4; ++nt) {
            short8 bf = *(const short8*)&Bs[nt * 16 + l16][quad * 8];
            acc[nt] = __builtin_amdgcn_mfma_f32_16x16x32_bf16(af, bf, acc[nt], 0, 0, 0);
        }
        __syncthreads();
    }
    // C/D layout: col = lane&15, row = quad*4 + reg
    #pragma unroll
    for (int r = 0; r < 4; ++r) {
        int row = bm + wave * 16 + quad * 4 + r;
        if (row < M) {
            float dv = dis[row];
            float* yrow = Y + (size_t)row * HID + bn + l16;
            #pragma unroll
            for (int nt = 0; nt < 4; ++nt) yrow[nt * 16] = dv * acc[nt][r];
        }
    }
    #undef LDT
}

// one wave per node: H[v,:] = bf16(relu(dis[v]*(sum_{u in N(v)} Y[u,:] + Y[v,:]) + b))
__global__ __launch_bounds__(256) void agg_kernel(
        const float* __restrict__ Y, const int* __restrict__ row_ptr,
        const int* __restrict__ col, const float* __restrict__ dis,
        const float* __restrict__ bias, unsigned short* __restrict__ H, int n) {
    int node = blockIdx.x * 4 + (threadIdx.x >> 6);
    if (node >= n) return;
    int lane = threadIdx.x & 63;
    const float4* Yv = (const float4*)Y;
    float4 acc = Yv[(size_t)node * 64 + lane];  // self loop
    int e = row_ptr[node], end = row_ptr[node + 1];
    for (; e + 1 < end; e += 2) {
        int u0 = col[e], u1 = col[e + 1];
        float4 m0 = Yv[(size_t)u0 * 64 + lane];
        float4 m1 = Yv[(size_t)u1 * 64 + lane];
        acc.x += m0.x + m1.x; acc.y += m0.y + m1.y;
        acc.z += m0.z + m1.z; acc.w += m0.w + m1.w;
    }
    if (e < end) {
        int u = col[e];
        float4 m = Yv[(size_t)u * 64 + lane];
        acc.x += m.x; acc.y += m.y; acc.z += m.z; acc.w += m.w;
    }
    float dv = dis[node];
    float4 b = ((const float4*)bias)[lane];
    ushort4 o;
    o.x = f2bf(fmaxf(fmaf(dv, acc.x, b.x), 0.f));
    o.y = f2bf(fmaxf(fmaf(dv, acc.y, b.y), 0.f));
    o.z = f2bf(fmaxf(fmaf(dv, acc.z, b.z), 0.f));
    o.w = f2bf(fmaxf(fmaf(dv, acc.w, b.w), 0.f));
    ((ushort4*)H)[(size_t)node * 64 + lane] = o;
}

// one block per graph: mean-pool (bf16 H) + concat + FC1(relu) + FC2
__global__ __launch_bounds__(256) void pool_mlp_kernel(
        const unsigned short* __restrict__ H, const int* __restrict__ goff,
        const float* __restrict__ mol, const float* __restrict__ rings,
        const float* __restrict__ fcW1, const float* __restrict__ fcb1,
        const float* __restrict__ fcW2, const float* __restrict__ fcb2,
        float* __restrict__ out) {
    __shared__ float s_hg[258];
    __shared__ float s_t[196];
    int g = blockIdx.x, tid = threadIdx.x;
    int beg = goff[g], end = goff[g + 1];
    float acc = 0.f;
    for (int i = beg; i < end; ++i) acc += bf2f(H[(size_t)i * HID + tid]);
    s_hg[tid] = acc / fmaxf((float)(end - beg), 1.0f);
    if (tid == 0) { s_hg[256] = mol[g]; s_hg[257] = rings[g]; }
    __syncthreads();
    if (tid < 196) {
        float a = fcb1[tid];
        for (int k = 0; k < 258; ++k) a = fmaf(s_hg[k], fcW1[k * 196 + tid], a);
        s_t[tid] = fmaxf(a, 0.f);
    }
    __syncthreads();
    if (tid < 16) {
        float a = fcb2[tid];
        for (int k = 0; k < 196; ++k) a = fmaf(s_t[k], fcW2[k * 16 + tid], a);
        out[g * 16 + tid] = a;
    }
}

extern "C" void kernel_launch(void* const* d_in, const int* in_sizes, int n_in,
                              void* d_out, int out_size, void* d_ws, size_t ws_size,
                              hipStream_t stream) {
    const float* x     = (const float*)d_in[0];
    const int*   ei    = (const int*)d_in[1];
    const int*   batch = (const int*)d_in[2];
    const float* mol   = (const float*)d_in[3];
    const float* rings = (const float*)d_in[4];
    const float* W1 = (const float*)d_in[5];
    const float* b1 = (const float*)d_in[6];
    const float* W2 = (const float*)d_in[7];
    const float* b2 = (const float*)d_in[8];
    const float* W3 = (const float*)d_in[9];
    const float* b3 = (const float*)d_in[10];
    const float* fcW1 = (const float*)d_in[11];
    const float* fcb1 = (const float*)d_in[12];
    const float* fcW2 = (const float*)d_in[13];
    const float* fcb2 = (const float*)d_in[14];
    float* out = (float*)d_out;
    const int* src = ei;
    const int* dst = ei + NE;

    char* w = (char*)d_ws;
    auto alloc = [&](size_t bytes) {
        char* p = w;
        w += (bytes + 255) & ~(size_t)255;
        return p;
    };
    int*   cnt     = (int*)alloc((size_t)NN * 4);
    int*   row_ptr = (int*)alloc((size_t)(NN + 1) * 4);
    int*   cursor  = (int*)alloc((size_t)NN * 4);
    int*   gcnt    = (int*)alloc((size_t)NG * 4);
    int*   goff    = (int*)alloc((size_t)(NG + 1) * 4);
    int*   bsum    = (int*)alloc((size_t)256 * 4);
    int*   boff    = (int*)alloc((size_t)257 * 4);
    float* dis     = (float*)alloc((size_t)NN * 4);
    int*   col     = (int*)alloc((size_t)NE * 4);
    unsigned short* Xb  = (unsigned short*)alloc((size_t)NN * FIN * 2);
    unsigned short* Hb  = (unsigned short*)alloc((size_t)NN * HID * 2);
    unsigned short* W1t = (unsigned short*)alloc((size_t)FIN * HID * 2);
    unsigned short* W2t = (unsigned short*)alloc((size_t)HID * HID * 2);
    unsigned short* W3t = (unsigned short*)alloc((size_t)HID * HID * 2);
    float* Y       = (float*)alloc((size_t)NN * HID * 4);

    hipMemsetAsync(cnt, 0, (size_t)NN * 4, stream);
    hipMemsetAsync(gcnt, 0, (size_t)NG * 4, stream);
    count_kernel<<<cdiv(NE, 256), 256, 0, stream>>>(dst, cnt, NE);
    count_kernel<<<cdiv(NN, 256), 256, 0, stream>>>(batch, gcnt, NN);
    dis_kernel<<<cdiv(NN, 256), 256, 0, stream>>>(cnt, dis, NN);

    // hierarchical scan of cnt -> row_ptr
    int nb = cdiv(NN, 256);  // 196
    block_reduce_kernel<<<nb, 256, 0, stream>>>(cnt, bsum, NN);
    scan_kernel<<<1, 256, 0, stream>>>(bsum, boff, nb);
    scan_add_kernel<<<nb, 256, 0, stream>>>(cnt, boff, row_ptr, NN);
    scan_kernel<<<1, 256, 0, stream>>>(gcnt, goff, NG);

    hipMemcpyAsync(cursor, row_ptr, (size_t)NN * 4, hipMemcpyDeviceToDevice, stream);
    fill_kernel<<<cdiv(NE, 256), 256, 0, stream>>>(src, dst, cursor, col, NE);

    // bf16 conversions
    cast_bf16_kernel<<<cdiv(NN * FIN / 4, 256), 256, 0, stream>>>(x, Xb, NN * FIN / 4);
    tcast_kernel<<<cdiv(FIN * 256, 256), 256, 0, stream>>>(W1, W1t, FIN);
    tcast_kernel<<<cdiv(HID * 256, 256), 256, 0, stream>>>(W2, W2t, HID);
    tcast_kernel<<<cdiv(HID * 256, 256), 256, 0, stream>>>(W3, W3t, HID);

    dim3 ggrid(cdiv(NN, 64), 4);
    int agrid = cdiv(NN, 4);
    gemm_bf16_kernel<<<ggrid, 256, 0, stream>>>(Xb, W1t, dis, Y, NN, FIN);
    agg_kernel<<<agrid, 256, 0, stream>>>(Y, row_ptr, col, dis, b1, Hb, NN);
    gemm_bf16_kernel<<<ggrid, 256, 0, stream>>>(Hb, W2t, dis, Y, NN, HID);
    agg_kernel<<<agrid, 256, 0, stream>>>(Y, row_ptr, col, dis, b2, Hb, NN);
    gemm_bf16_kernel<<<ggrid, 256, 0, stream>>>(Hb, W3t, dis, Y, NN, HID);
    agg_kernel<<<agrid, 256, 0, stream>>>(Y, row_ptr, col, dis, b3, Hb, NN);
    pool_mlp_kernel<<<NG, 256, 0, stream>>>(Hb, goff, mol, rings, fcW1, fcb1, fcW2, fcb2, out);
}

// Round 3
// 530.677 us; speedup vs baseline: 1.9494x; 1.2922x over previous
//
#include <hip/hip_runtime.h>

#define NN 50000
#define NE 800000
#define NG 512
#define FIN 128
#define HID 256

typedef short short8 __attribute__((ext_vector_type(8)));
typedef float f32x4 __attribute__((ext_vector_type(4)));

static inline int cdiv(int a, int b) { return (a + b - 1) / b; }

static __device__ inline unsigned short f2bf(float f) {
    unsigned int u = __float_as_uint(f);
    unsigned int r = (u + 0x7FFF + ((u >> 16) & 1)) >> 16;  // RNE
    return (unsigned short)r;
}
static __device__ inline float bf2f(unsigned short h) {
    return __uint_as_float(((unsigned int)h) << 16);
}
// unpack uint (2 bf16) -> lo/hi floats
static __device__ inline float bflo(unsigned int p) { return __uint_as_float(p << 16); }
static __device__ inline float bfhi(unsigned int p) { return __uint_as_float(p & 0xFFFF0000u); }

// ---- histogram (also used for batch counts) ----
__global__ void count_kernel(const int* __restrict__ idx, int* __restrict__ cnt, int n) {
    int i = blockIdx.x * 256 + threadIdx.x;
    if (i < n) atomicAdd(&cnt[idx[i]], 1);
}

__global__ void dis_kernel(const int* __restrict__ cnt, float* __restrict__ dis, int n) {
    int i = blockIdx.x * 256 + threadIdx.x;
    if (i < n) dis[i] = rsqrtf((float)cnt[i] + 1.0f);
}

// single-block exclusive scan (small n only: NG=512, block partials=196)
__global__ void scan_kernel(const int* __restrict__ in, int* __restrict__ out, int n) {
    __shared__ int wsum[4];
    __shared__ int carry_s;
    int tid = threadIdx.x, lane = tid & 63, wid = tid >> 6;
    if (tid == 0) carry_s = 0;
    __syncthreads();
    for (int base = 0; base < n; base += 256) {
        int i = base + tid;
        int v = (i < n) ? in[i] : 0;
        int incl = v;
        #pragma unroll
        for (int off = 1; off < 64; off <<= 1) {
            int u = __shfl_up(incl, off, 64);
            if (lane >= off) incl += u;
        }
        if (lane == 63) wsum[wid] = incl;
        __syncthreads();
        int woff = 0;
        for (int w = 0; w < wid; ++w) woff += wsum[w];
        int total = wsum[0] + wsum[1] + wsum[2] + wsum[3];
        if (i < n) out[i] = carry_s + woff + incl - v;
        __syncthreads();
        if (tid == 0) carry_s += total;
        __syncthreads();
    }
    if (threadIdx.x == 0) out[n] = carry_s;
}

// hierarchical scan pass 1: per-block sum of 256 ints
__global__ void block_reduce_kernel(const int* __restrict__ in, int* __restrict__ bsum, int n) {
    int i = blockIdx.x * 256 + threadIdx.x;
    int v = (i < n) ? in[i] : 0;
    #pragma unroll
    for (int off = 32; off; off >>= 1) v += __shfl_down(v, off, 64);
    __shared__ int ws[4];
    if ((threadIdx.x & 63) == 0) ws[threadIdx.x >> 6] = v;
    __syncthreads();
    if (threadIdx.x == 0) bsum[blockIdx.x] = ws[0] + ws[1] + ws[2] + ws[3];
}

// hierarchical scan pass 3: local exclusive scan + block offset
__global__ void scan_add_kernel(const int* __restrict__ in, const int* __restrict__ boff,
                                int* __restrict__ out, int n) {
    int b = blockIdx.x, tid = threadIdx.x;
    int i = b * 256 + tid;
    int lane = tid & 63, wid = tid >> 6;
    int v = (i < n) ? in[i] : 0;
    int incl = v;
    #pragma unroll
    for (int off = 1; off < 64; off <<= 1) {
        int u = __shfl_up(incl, off, 64);
        if (lane >= off) incl += u;
    }
    __shared__ int ws[4];
    if (lane == 63) ws[wid] = incl;
    __syncthreads();
    int woff = 0;
    for (int w = 0; w < wid; ++w) woff += ws[w];
    if (i < n) out[i] = boff[b] + woff + incl - v;
    if (b == 0 && tid == 0) out[n] = boff[gridDim.x];
}

__global__ void fill_kernel(const int* __restrict__ src, const int* __restrict__ dst,
                            int* __restrict__ cursor, int* __restrict__ col, int n) {
    int i = blockIdx.x * 256 + threadIdx.x;
    if (i < n) {
        int pos = atomicAdd(&cursor[dst[i]], 1);
        col[pos] = src[i];
    }
}

// cast fp32 -> bf16, vectorized
__global__ void cast_bf16_kernel(const float* __restrict__ in, unsigned short* __restrict__ out, int n4) {
    int i = blockIdx.x * 256 + threadIdx.x;
    if (i < n4) {
        float4 v = ((const float4*)in)[i];
        ushort4 o;
        o.x = f2bf(v.x); o.y = f2bf(v.y); o.z = f2bf(v.z); o.w = f2bf(v.w);
        ((ushort4*)out)[i] = o;
    }
}

// W [K,256] fp32 -> Wt [256,K] bf16
__global__ void tcast_kernel(const float* __restrict__ W, unsigned short* __restrict__ Wt, int K) {
    int idx = blockIdx.x * 256 + threadIdx.x;
    int total = K * 256;
    if (idx < total) {
        int n = idx / K, k = idx - n * K;
        Wt[idx] = f2bf(W[(size_t)k * 256 + n]);
    }
}

// Y[i,:] = bf16(dis[i] * (A[i,:] @ B))  A:[M,K] bf16, Bt:[256,K] bf16, Y:[M,256] bf16
__global__ __launch_bounds__(256) void gemm_bf16_kernel(
        const unsigned short* __restrict__ A, const unsigned short* __restrict__ Bt,
        const float* __restrict__ dis, unsigned short* __restrict__ Y, int M, int K) {
    #define LDT 40
    __shared__ unsigned short As[64][LDT];
    __shared__ unsigned short Bs[64][LDT];
    const int tid = threadIdx.x;
    const int bm = blockIdx.x * 64, bn = blockIdx.y * 64;
    const int wave = tid >> 6, lane = tid & 63;
    const int l16 = lane & 15, quad = lane >> 4;
    const int lr = tid >> 2, lc = (tid & 3) * 8;

    f32x4 acc[4];
    #pragma unroll
    for (int i = 0; i < 4; ++i) acc[i] = (f32x4){0.f, 0.f, 0.f, 0.f};

    const int arow = bm + lr;
    for (int k0 = 0; k0 < K; k0 += 32) {
        uint4 av = make_uint4(0, 0, 0, 0);
        if (arow < M) av = *(const uint4*)(A + (size_t)arow * K + k0 + lc);
        *(uint4*)&As[lr][lc] = av;
        uint4 bv = *(const uint4*)(Bt + (size_t)(bn + lr) * K + k0 + lc);
        *(uint4*)&Bs[lr][lc] = bv;
        __syncthreads();
        short8 af = *(const short8*)&As[wave * 16 + l16][quad * 8];
        #pragma unroll
        for (int nt = 0; nt < 4; ++nt) {
            short8 bf = *(const short8*)&Bs[nt * 16 + l16][quad * 8];
            acc[nt] = __builtin_amdgcn_mfma_f32_16x16x32_bf16(af, bf, acc[nt], 0, 0, 0);
        }
        __syncthreads();
    }
    // C/D layout: col = lane&15 (+16*nt), row = quad*4 + reg
    #pragma unroll
    for (int r = 0; r < 4; ++r) {
        int row = bm + wave * 16 + quad * 4 + r;
        if (row < M) {
            float dv = dis[row];
            unsigned short* yrow = Y + (size_t)row * HID + bn + l16;
            #pragma unroll
            for (int nt = 0; nt < 4; ++nt) yrow[nt * 16] = f2bf(dv * acc[nt][r]);
        }
    }
    #undef LDT
}

// one wave per node: H[v,:] = bf16(relu(dis[v]*(sum_{u in N(v)} Y[u,:] + Y[v,:]) + b))
// Y bf16: lane holds features 4*lane..4*lane+3 (one uint2 = 4 bf16)
__global__ __launch_bounds__(256) void agg_kernel(
        const unsigned short* __restrict__ Y, const int* __restrict__ row_ptr,
        const int* __restrict__ col, const float* __restrict__ dis,
        const float* __restrict__ bias, unsigned short* __restrict__ H, int n) {
    int node = blockIdx.x * 4 + (threadIdx.x >> 6);
    if (node >= n) return;
    int lane = threadIdx.x & 63;
    const uint2* Yv = (const uint2*)Y;
    uint2 p = Yv[(size_t)node * 64 + lane];  // self loop
    float4 acc = make_float4(bflo(p.x), bfhi(p.x), bflo(p.y), bfhi(p.y));
    int e = row_ptr[node], end = row_ptr[node + 1];
    for (; e + 3 < end; e += 4) {
        int u0 = col[e], u1 = col[e + 1], u2 = col[e + 2], u3 = col[e + 3];
        uint2 m0 = Yv[(size_t)u0 * 64 + lane];
        uint2 m1 = Yv[(size_t)u1 * 64 + lane];
        uint2 m2 = Yv[(size_t)u2 * 64 + lane];
        uint2 m3 = Yv[(size_t)u3 * 64 + lane];
        acc.x += (bflo(m0.x) + bflo(m1.x)) + (bflo(m2.x) + bflo(m3.x));
        acc.y += (bfhi(m0.x) + bfhi(m1.x)) + (bfhi(m2.x) + bfhi(m3.x));
        acc.z += (bflo(m0.y) + bflo(m1.y)) + (bflo(m2.y) + bflo(m3.y));
        acc.w += (bfhi(m0.y) + bfhi(m1.y)) + (bfhi(m2.y) + bfhi(m3.y));
    }
    for (; e < end; ++e) {
        int u = col[e];
        uint2 m = Yv[(size_t)u * 64 + lane];
        acc.x += bflo(m.x); acc.y += bfhi(m.x);
        acc.z += bflo(m.y); acc.w += bfhi(m.y);
    }
    float dv = dis[node];
    float4 b = ((const float4*)bias)[lane];
    ushort4 o;
    o.x = f2bf(fmaxf(fmaf(dv, acc.x, b.x), 0.f));
    o.y = f2bf(fmaxf(fmaf(dv, acc.y, b.y), 0.f));
    o.z = f2bf(fmaxf(fmaf(dv, acc.z, b.z), 0.f));
    o.w = f2bf(fmaxf(fmaf(dv, acc.w, b.w), 0.f));
    ((ushort4*)H)[(size_t)node * 64 + lane] = o;
}

// one block per graph: mean-pool (bf16 H) + concat + FC1(relu) + FC2
__global__ __launch_bounds__(256) void pool_mlp_kernel(
        const unsigned short* __restrict__ H, const int* __restrict__ goff,
        const float* __restrict__ mol, const float* __restrict__ rings,
        const float* __restrict__ fcW1, const float* __restrict__ fcb1,
        const float* __restrict__ fcW2, const float* __restrict__ fcb2,
        float* __restrict__ out) {
    __shared__ float s_hg[258];
    __shared__ float s_t[196];
    int g = blockIdx.x, tid = threadIdx.x;
    int beg = goff[g], end = goff[g + 1];
    float acc = 0.f;
    for (int i = beg; i < end; ++i) acc += bf2f(H[(size_t)i * HID + tid]);
    s_hg[tid] = acc / fmaxf((float)(end - beg), 1.0f);
    if (tid == 0) { s_hg[256] = mol[g]; s_hg[257] = rings[g]; }
    __syncthreads();
    if (tid < 196) {
        float a = fcb1[tid];
        for (int k = 0; k < 258; ++k) a = fmaf(s_hg[k], fcW1[k * 196 + tid], a);
        s_t[tid] = fmaxf(a, 0.f);
    }
    __syncthreads();
    if (tid < 16) {
        float a = fcb2[tid];
        for (int k = 0; k < 196; ++k) a = fmaf(s_t[k], fcW2[k * 16 + tid], a);
        out[g * 16 + tid] = a;
    }
}

extern "C" void kernel_launch(void* const* d_in, const int* in_sizes, int n_in,
                              void* d_out, int out_size, void* d_ws, size_t ws_size,
                              hipStream_t stream) {
    const float* x     = (const float*)d_in[0];
    const int*   ei    = (const int*)d_in[1];
    const int*   batch = (const int*)d_in[2];
    const float* mol   = (const float*)d_in[3];
    const float* rings = (const float*)d_in[4];
    const float* W1 = (const float*)d_in[5];
    const float* b1 = (const float*)d_in[6];
    const float* W2 = (const float*)d_in[7];
    const float* b2 = (const float*)d_in[8];
    const float* W3 = (const float*)d_in[9];
    const float* b3 = (const float*)d_in[10];
    const float* fcW1 = (const float*)d_in[11];
    const float* fcb1 = (const float*)d_in[12];
    const float* fcW2 = (const float*)d_in[13];
    const float* fcb2 = (const float*)d_in[14];
    float* out = (float*)d_out;
    const int* src = ei;
    const int* dst = ei + NE;

    char* w = (char*)d_ws;
    auto alloc = [&](size_t bytes) {
        char* p = w;
        w += (bytes + 255) & ~(size_t)255;
        return p;
    };
    int*   cnt     = (int*)alloc((size_t)NN * 4);
    int*   row_ptr = (int*)alloc((size_t)(NN + 1) * 4);
    int*   cursor  = (int*)alloc((size_t)NN * 4);
    int*   gcnt    = (int*)alloc((size_t)NG * 4);
    int*   goff    = (int*)alloc((size_t)(NG + 1) * 4);
    int*   bsum    = (int*)alloc((size_t)256 * 4);
    int*   boff    = (int*)alloc((size_t)257 * 4);
    float* dis     = (float*)alloc((size_t)NN * 4);
    int*   col     = (int*)alloc((size_t)NE * 4);
    unsigned short* Xb  = (unsigned short*)alloc((size_t)NN * FIN * 2);
    unsigned short* Hb  = (unsigned short*)alloc((size_t)NN * HID * 2);
    unsigned short* W1t = (unsigned short*)alloc((size_t)FIN * HID * 2);
    unsigned short* W2t = (unsigned short*)alloc((size_t)HID * HID * 2);
    unsigned short* W3t = (unsigned short*)alloc((size_t)HID * HID * 2);
    unsigned short* Yb  = (unsigned short*)alloc((size_t)NN * HID * 2);

    hipMemsetAsync(cnt, 0, (size_t)NN * 4, stream);
    hipMemsetAsync(gcnt, 0, (size_t)NG * 4, stream);
    count_kernel<<<cdiv(NE, 256), 256, 0, stream>>>(dst, cnt, NE);
    count_kernel<<<cdiv(NN, 256), 256, 0, stream>>>(batch, gcnt, NN);
    dis_kernel<<<cdiv(NN, 256), 256, 0, stream>>>(cnt, dis, NN);

    int nb = cdiv(NN, 256);  // 196
    block_reduce_kernel<<<nb, 256, 0, stream>>>(cnt, bsum, NN);
    scan_kernel<<<1, 256, 0, stream>>>(bsum, boff, nb);
    scan_add_kernel<<<nb, 256, 0, stream>>>(cnt, boff, row_ptr, NN);
    scan_kernel<<<1, 256, 0, stream>>>(gcnt, goff, NG);

    hipMemcpyAsync(cursor, row_ptr, (size_t)NN * 4, hipMemcpyDeviceToDevice, stream);
    fill_kernel<<<cdiv(NE, 256), 256, 0, stream>>>(src, dst, cursor, col, NE);

    cast_bf16_kernel<<<cdiv(NN * FIN / 4, 256), 256, 0, stream>>>(x, Xb, NN * FIN / 4);
    tcast_kernel<<<cdiv(FIN * 256, 256), 256, 0, stream>>>(W1, W1t, FIN);
    tcast_kernel<<<cdiv(HID * 256, 256), 256, 0, stream>>>(W2, W2t, HID);
    tcast_kernel<<<cdiv(HID * 256, 256), 256, 0, stream>>>(W3, W3t, HID);

    dim3 ggrid(cdiv(NN, 64), 4);
    int agrid = cdiv(NN, 4);
    gemm_bf16_kernel<<<ggrid, 256, 0, stream>>>(Xb, W1t, dis, Yb, NN, FIN);
    agg_kernel<<<agrid, 256, 0, stream>>>(Yb, row_ptr, col, dis, b1, Hb, NN);
    gemm_bf16_kernel<<<ggrid, 256, 0, stream>>>(Hb, W2t, dis, Yb, NN, HID);
    agg_kernel<<<agrid, 256, 0, stream>>>(Yb, row_ptr, col, dis, b2, Hb, NN);
    gemm_bf16_kernel<<<ggrid, 256, 0, stream>>>(Hb, W3t, dis, Yb, NN, HID);
    agg_kernel<<<agrid, 256, 0, stream>>>(Yb, row_ptr, col, dis, b3, Hb, NN);
    pool_mlp_kernel<<<NG, 256, 0, stream>>>(Hb, goff, mol, rings, fcW1, fcb1, fcW2, fcb2, out);
}

// Round 4
// 506.912 us; speedup vs baseline: 2.0408x; 1.0469x over previous
//
#include <hip/hip_runtime.h>

#define NN 50000
#define NE 800000
#define NG 512
#define FIN 128
#define HID 256

typedef short short8 __attribute__((ext_vector_type(8)));
typedef float f32x4 __attribute__((ext_vector_type(4)));

static inline int cdiv(int a, int b) { return (a + b - 1) / b; }

static __device__ inline unsigned short f2bf(float f) {
    unsigned int u = __float_as_uint(f);
    unsigned int r = (u + 0x7FFF + ((u >> 16) & 1)) >> 16;  // RNE
    return (unsigned short)r;
}
static __device__ inline float bf2f(unsigned short h) {
    return __uint_as_float(((unsigned int)h) << 16);
}
static __device__ inline float bflo(unsigned int p) { return __uint_as_float(p << 16); }
static __device__ inline float bfhi(unsigned int p) { return __uint_as_float(p & 0xFFFF0000u); }

typedef __attribute__((address_space(1))) unsigned int gu32;
typedef __attribute__((address_space(3))) unsigned int lu32;
static __device__ __forceinline__ void gload16(const unsigned short* g, unsigned short* l) {
    __builtin_amdgcn_global_load_lds((const gu32*)(const void*)g, (lu32*)(void*)l, 16, 0, 0);
}

// ---- histogram ----
__global__ void count_kernel(const int* __restrict__ idx, int* __restrict__ cnt, int n) {
    int i = blockIdx.x * 256 + threadIdx.x;
    if (i < n) atomicAdd(&cnt[idx[i]], 1);
}

__global__ void dis_kernel(const int* __restrict__ cnt, float* __restrict__ dis, int n) {
    int i = blockIdx.x * 256 + threadIdx.x;
    if (i < n) dis[i] = rsqrtf((float)cnt[i] + 1.0f);
}

// single-block exclusive scan (small n: NG=512, block partials=196)
__global__ void scan_kernel(const int* __restrict__ in, int* __restrict__ out, int n) {
    __shared__ int wsum[4];
    __shared__ int carry_s;
    int tid = threadIdx.x, lane = tid & 63, wid = tid >> 6;
    if (tid == 0) carry_s = 0;
    __syncthreads();
    for (int base = 0; base < n; base += 256) {
        int i = base + tid;
        int v = (i < n) ? in[i] : 0;
        int incl = v;
        #pragma unroll
        for (int off = 1; off < 64; off <<= 1) {
            int u = __shfl_up(incl, off, 64);
            if (lane >= off) incl += u;
        }
        if (lane == 63) wsum[wid] = incl;
        __syncthreads();
        int woff = 0;
        for (int w = 0; w < wid; ++w) woff += wsum[w];
        int total = wsum[0] + wsum[1] + wsum[2] + wsum[3];
        if (i < n) out[i] = carry_s + woff + incl - v;
        __syncthreads();
        if (tid == 0) carry_s += total;
        __syncthreads();
    }
    if (threadIdx.x == 0) out[n] = carry_s;
}

__global__ void block_reduce_kernel(const int* __restrict__ in, int* __restrict__ bsum, int n) {
    int i = blockIdx.x * 256 + threadIdx.x;
    int v = (i < n) ? in[i] : 0;
    #pragma unroll
    for (int off = 32; off; off >>= 1) v += __shfl_down(v, off, 64);
    __shared__ int ws[4];
    if ((threadIdx.x & 63) == 0) ws[threadIdx.x >> 6] = v;
    __syncthreads();
    if (threadIdx.x == 0) bsum[blockIdx.x] = ws[0] + ws[1] + ws[2] + ws[3];
}

__global__ void scan_add_kernel(const int* __restrict__ in, const int* __restrict__ boff,
                                int* __restrict__ out, int n) {
    int b = blockIdx.x, tid = threadIdx.x;
    int i = b * 256 + tid;
    int lane = tid & 63, wid = tid >> 6;
    int v = (i < n) ? in[i] : 0;
    int incl = v;
    #pragma unroll
    for (int off = 1; off < 64; off <<= 1) {
        int u = __shfl_up(incl, off, 64);
        if (lane >= off) incl += u;
    }
    __shared__ int ws[4];
    if (lane == 63) ws[wid] = incl;
    __syncthreads();
    int woff = 0;
    for (int w = 0; w < wid; ++w) woff += ws[w];
    if (i < n) out[i] = boff[b] + woff + incl - v;
    if (b == 0 && tid == 0) out[n] = boff[gridDim.x];
}

__global__ void fill_kernel(const int* __restrict__ src, const int* __restrict__ dst,
                            int* __restrict__ cursor, int* __restrict__ col, int n) {
    int i = blockIdx.x * 256 + threadIdx.x;
    if (i < n) {
        int pos = atomicAdd(&cursor[dst[i]], 1);
        col[pos] = src[i];
    }
}

// Xs[i][f] = bf16(dis[i] * x[i][f])  (128 features -> 32 float4 per row)
__global__ void cast_scale_kernel(const float* __restrict__ x, const float* __restrict__ dis,
                                  unsigned short* __restrict__ Xs, int n4) {
    int i = blockIdx.x * 256 + threadIdx.x;
    if (i < n4) {
        float dv = dis[i >> 5];
        float4 v = ((const float4*)x)[i];
        ushort4 o;
        o.x = f2bf(dv * v.x); o.y = f2bf(dv * v.y); o.z = f2bf(dv * v.z); o.w = f2bf(dv * v.w);
        ((ushort4*)Xs)[i] = o;
    }
}

// W [K,256] fp32 -> Wt [256,K] bf16
__global__ void tcast_kernel(const float* __restrict__ W, unsigned short* __restrict__ Wt, int K) {
    int idx = blockIdx.x * 256 + threadIdx.x;
    int total = K * 256;
    if (idx < total) {
        int n = idx / K, k = idx - n * K;
        Wt[idx] = f2bf(W[(size_t)k * 256 + n]);
    }
}

// m97-style 128x128 GEMM, BK=32, global_load_lds staging.
// A:[M,K] bf16, Bt:[NB,K] bf16 (N-major).  MODE 0: C = bf16(dis[row]*acc)
// MODE 1: C = bf16(relu(acc + bias[col])).  C:[M,256] bf16.
template <int MODE>
__global__ __launch_bounds__(256) void gemm128_kernel(
        const unsigned short* __restrict__ A, const unsigned short* __restrict__ Bt,
        const float* __restrict__ dis, const float* __restrict__ bias,
        unsigned short* __restrict__ C, int M, int K) {
    __shared__ unsigned short As[128 * 32];   // row-major [128][32], unpadded (glds constraint)
    __shared__ unsigned short Bs[128 * 32];
    const int tid = threadIdx.x;
    const int bm = blockIdx.x * 128, bn = blockIdx.y * 128;
    const int wave = tid >> 6, lane = tid & 63;
    const int l16 = lane & 15, quad = lane >> 4;
    const int wm = (wave & 1) * 64, wn = (wave >> 1) * 64;

    // staging chunks: c = r*256 + tid -> row = c>>2, kc = (c&3)*8 elements
    int srow0 = tid >> 2, skc0 = (tid & 3) * 8;
    int srow1 = (256 + tid) >> 2, skc1 = skc0;  // (c&3) identical

    int ar0 = bm + srow0; if (ar0 > M - 1) ar0 = M - 1;
    int ar1 = bm + srow1; if (ar1 > M - 1) ar1 = M - 1;

    f32x4 acc[4][4];
    #pragma unroll
    for (int i = 0; i < 4; ++i)
        #pragma unroll
        for (int j = 0; j < 4; ++j) acc[i][j] = (f32x4){0.f, 0.f, 0.f, 0.f};

    for (int k0 = 0; k0 < K; k0 += 32) {
        gload16(A + (size_t)ar0 * K + k0 + skc0, &As[(size_t)tid * 8]);
        gload16(A + (size_t)ar1 * K + k0 + skc1, &As[(size_t)(256 + tid) * 8]);
        gload16(Bt + (size_t)(bn + srow0) * K + k0 + skc0, &Bs[(size_t)tid * 8]);
        gload16(Bt + (size_t)(bn + srow1) * K + k0 + skc1, &Bs[(size_t)(256 + tid) * 8]);
        __syncthreads();
        short8 af[4], bf[4];
        #pragma unroll
        for (int mt = 0; mt < 4; ++mt) af[mt] = *(const short8*)&As[(wm + mt * 16 + l16) * 32 + quad * 8];
        #pragma unroll
        for (int nt = 0; nt < 4; ++nt) bf[nt] = *(const short8*)&Bs[(wn + nt * 16 + l16) * 32 + quad * 8];
        #pragma unroll
        for (int mt = 0; mt < 4; ++mt)
            #pragma unroll
            for (int nt = 0; nt < 4; ++nt)
                acc[mt][nt] = __builtin_amdgcn_mfma_f32_16x16x32_bf16(af[mt], bf[nt], acc[mt][nt], 0, 0, 0);
        __syncthreads();
    }
    // C/D: col = l16 (+16*nt), row = quad*4 + reg
    #pragma unroll
    for (int mt = 0; mt < 4; ++mt) {
        #pragma unroll
        for (int r = 0; r < 4; ++r) {
            int row = bm + wm + mt * 16 + quad * 4 + r;
            if (row < M) {
                unsigned short* crow = C + (size_t)row * HID + bn + wn + l16;
                if (MODE == 0) {
                    float dv = dis[row];
                    #pragma unroll
                    for (int nt = 0; nt < 4; ++nt) crow[nt * 16] = f2bf(dv * acc[mt][nt][r]);
                } else {
                    #pragma unroll
                    for (int nt = 0; nt < 4; ++nt) {
                        float bv = bias[bn + wn + nt * 16 + l16];
                        crow[nt * 16] = f2bf(fmaxf(acc[mt][nt][r] + bv, 0.f));
                    }
                }
            }
        }
    }
}

// layer-1 aggregation over Xs (128 features, 4B/lane): Xa[v] = bf16(dis[v]*(sum_N Xs[u] + Xs[v]))
__global__ __launch_bounds__(256) void agg128_kernel(
        const unsigned short* __restrict__ Xs, const int* __restrict__ row_ptr,
        const int* __restrict__ col, const float* __restrict__ dis,
        unsigned short* __restrict__ Xa, int n) {
    int node = blockIdx.x * 4 + (threadIdx.x >> 6);
    if (node >= n) return;
    int lane = threadIdx.x & 63;
    const unsigned int* Xv = (const unsigned int*)Xs;
    unsigned int p = Xv[(size_t)node * 64 + lane];  // self loop
    float ax = bflo(p), ay = bfhi(p);
    int e = row_ptr[node], end = row_ptr[node + 1];
    for (; e + 3 < end; e += 4) {
        unsigned int m0 = Xv[(size_t)col[e] * 64 + lane];
        unsigned int m1 = Xv[(size_t)col[e + 1] * 64 + lane];
        unsigned int m2 = Xv[(size_t)col[e + 2] * 64 + lane];
        unsigned int m3 = Xv[(size_t)col[e + 3] * 64 + lane];
        ax += (bflo(m0) + bflo(m1)) + (bflo(m2) + bflo(m3));
        ay += (bfhi(m0) + bfhi(m1)) + (bfhi(m2) + bfhi(m3));
    }
    for (; e < end; ++e) {
        unsigned int m = Xv[(size_t)col[e] * 64 + lane];
        ax += bflo(m); ay += bfhi(m);
    }
    float dv = dis[node];
    unsigned int o = (unsigned int)f2bf(dv * ax) | ((unsigned int)f2bf(dv * ay) << 16);
    ((unsigned int*)Xa)[(size_t)node * 64 + lane] = o;
}

// layers 2,3: H[v] = bf16(relu(dis[v]*(sum_N Y[u] + Y[v]) + b)), 256 features (8B/lane)
__global__ __launch_bounds__(256) void agg256_kernel(
        const unsigned short* __restrict__ Y, const int* __restrict__ row_ptr,
        const int* __restrict__ col, const float* __restrict__ dis,
        const float* __restrict__ bias, unsigned short* __restrict__ H, int n) {
    int node = blockIdx.x * 4 + (threadIdx.x >> 6);
    if (node >= n) return;
    int lane = threadIdx.x & 63;
    const uint2* Yv = (const uint2*)Y;
    uint2 p = Yv[(size_t)node * 64 + lane];
    float4 acc = make_float4(bflo(p.x), bfhi(p.x), bflo(p.y), bfhi(p.y));
    int e = row_ptr[node], end = row_ptr[node + 1];
    for (; e + 3 < end; e += 4) {
        uint2 m0 = Yv[(size_t)col[e] * 64 + lane];
        uint2 m1 = Yv[(size_t)col[e + 1] * 64 + lane];
        uint2 m2 = Yv[(size_t)col[e + 2] * 64 + lane];
        uint2 m3 = Yv[(size_t)col[e + 3] * 64 + lane];
        acc.x += (bflo(m0.x) + bflo(m1.x)) + (bflo(m2.x) + bflo(m3.x));
        acc.y += (bfhi(m0.x) + bfhi(m1.x)) + (bfhi(m2.x) + bfhi(m3.x));
        acc.z += (bflo(m0.y) + bflo(m1.y)) + (bflo(m2.y) + bflo(m3.y));
        acc.w += (bfhi(m0.y) + bfhi(m1.y)) + (bfhi(m2.y) + bfhi(m3.y));
    }
    for (; e < end; ++e) {
        uint2 m = Yv[(size_t)col[e] * 64 + lane];
        acc.x += bflo(m.x); acc.y += bfhi(m.x);
        acc.z += bflo(m.y); acc.w += bfhi(m.y);
    }
    float dv = dis[node];
    float4 b = ((const float4*)bias)[lane];
    ushort4 o;
    o.x = f2bf(fmaxf(fmaf(dv, acc.x, b.x), 0.f));
    o.y = f2bf(fmaxf(fmaf(dv, acc.y, b.y), 0.f));
    o.z = f2bf(fmaxf(fmaf(dv, acc.z, b.z), 0.f));
    o.w = f2bf(fmaxf(fmaf(dv, acc.w, b.w), 0.f));
    ((ushort4*)H)[(size_t)node * 64 + lane] = o;
}

// one block per graph: mean-pool (bf16 H) + concat + FC1(relu) + FC2
__global__ __launch_bounds__(256) void pool_mlp_kernel(
        const unsigned short* __restrict__ H, const int* __restrict__ goff,
        const float* __restrict__ mol, const float* __restrict__ rings,
        const float* __restrict__ fcW1, const float* __restrict__ fcb1,
        const float* __restrict__ fcW2, const float* __restrict__ fcb2,
        float* __restrict__ out) {
    __shared__ float s_hg[258];
    __shared__ float s_t[196];
    int g = blockIdx.x, tid = threadIdx.x;
    int beg = goff[g], end = goff[g + 1];
    float acc = 0.f;
    for (int i = beg; i < end; ++i) acc += bf2f(H[(size_t)i * HID + tid]);
    s_hg[tid] = acc / fmaxf((float)(end - beg), 1.0f);
    if (tid == 0) { s_hg[256] = mol[g]; s_hg[257] = rings[g]; }
    __syncthreads();
    if (tid < 196) {
        float a = fcb1[tid];
        for (int k = 0; k < 258; ++k) a = fmaf(s_hg[k], fcW1[k * 196 + tid], a);
        s_t[tid] = fmaxf(a, 0.f);
    }
    __syncthreads();
    if (tid < 16) {
        float a = fcb2[tid];
        for (int k = 0; k < 196; ++k) a = fmaf(s_t[k], fcW2[k * 16 + tid], a);
        out[g * 16 + tid] = a;
    }
}

extern "C" void kernel_launch(void* const* d_in, const int* in_sizes, int n_in,
                              void* d_out, int out_size, void* d_ws, size_t ws_size,
                              hipStream_t stream) {
    const float* x     = (const float*)d_in[0];
    const int*   ei    = (const int*)d_in[1];
    const int*   batch = (const int*)d_in[2];
    const float* mol   = (const float*)d_in[3];
    const float* rings = (const float*)d_in[4];
    const float* W1 = (const float*)d_in[5];
    const float* b1 = (const float*)d_in[6];
    const float* W2 = (const float*)d_in[7];
    const float* b2 = (const float*)d_in[8];
    const float* W3 = (const float*)d_in[9];
    const float* b3 = (const float*)d_in[10];
    const float* fcW1 = (const float*)d_in[11];
    const float* fcb1 = (const float*)d_in[12];
    const float* fcW2 = (const float*)d_in[13];
    const float* fcb2 = (const float*)d_in[14];
    float* out = (float*)d_out;
    const int* src = ei;
    const int* dst = ei + NE;

    char* w = (char*)d_ws;
    auto alloc = [&](size_t bytes) {
        char* p = w;
        w += (bytes + 255) & ~(size_t)255;
        return p;
    };
    int*   cnt     = (int*)alloc((size_t)NN * 4);
    int*   row_ptr = (int*)alloc((size_t)(NN + 1) * 4);
    int*   cursor  = (int*)alloc((size_t)NN * 4);
    int*   gcnt    = (int*)alloc((size_t)NG * 4);
    int*   goff    = (int*)alloc((size_t)(NG + 1) * 4);
    int*   bsum    = (int*)alloc((size_t)256 * 4);
    int*   boff    = (int*)alloc((size_t)257 * 4);
    float* dis     = (float*)alloc((size_t)NN * 4);
    int*   col     = (int*)alloc((size_t)NE * 4);
    unsigned short* Xs  = (unsigned short*)alloc((size_t)NN * FIN * 2);
    unsigned short* Xa  = (unsigned short*)alloc((size_t)NN * FIN * 2);
    unsigned short* Hb  = (unsigned short*)alloc((size_t)NN * HID * 2);
    unsigned short* W1t = (unsigned short*)alloc((size_t)FIN * HID * 2);
    unsigned short* W2t = (unsigned short*)alloc((size_t)HID * HID * 2);
    unsigned short* W3t = (unsigned short*)alloc((size_t)HID * HID * 2);
    unsigned short* Yb  = (unsigned short*)alloc((size_t)NN * HID * 2);

    hipMemsetAsync(cnt, 0, (size_t)NN * 4, stream);
    hipMemsetAsync(gcnt, 0, (size_t)NG * 4, stream);
    count_kernel<<<cdiv(NE, 256), 256, 0, stream>>>(dst, cnt, NE);
    count_kernel<<<cdiv(NN, 256), 256, 0, stream>>>(batch, gcnt, NN);
    dis_kernel<<<cdiv(NN, 256), 256, 0, stream>>>(cnt, dis, NN);

    int nb = cdiv(NN, 256);  // 196
    block_reduce_kernel<<<nb, 256, 0, stream>>>(cnt, bsum, NN);
    scan_kernel<<<1, 256, 0, stream>>>(bsum, boff, nb);
    scan_add_kernel<<<nb, 256, 0, stream>>>(cnt, boff, row_ptr, NN);
    scan_kernel<<<1, 256, 0, stream>>>(gcnt, goff, NG);

    hipMemcpyAsync(cursor, row_ptr, (size_t)NN * 4, hipMemcpyDeviceToDevice, stream);
    fill_kernel<<<cdiv(NE, 256), 256, 0, stream>>>(src, dst, cursor, col, NE);

    cast_scale_kernel<<<cdiv(NN * FIN / 4, 256), 256, 0, stream>>>(x, dis, Xs, NN * FIN / 4);
    tcast_kernel<<<cdiv(FIN * 256, 256), 256, 0, stream>>>(W1, W1t, FIN);
    tcast_kernel<<<cdiv(HID * 256, 256), 256, 0, stream>>>(W2, W2t, HID);
    tcast_kernel<<<cdiv(HID * 256, 256), 256, 0, stream>>>(W3, W3t, HID);

    dim3 ggrid(cdiv(NN, 128), 2);
    int agrid = cdiv(NN, 4);
    // layer 1: aggregate-then-transform (W is linear; 128-wide gather)
    agg128_kernel<<<agrid, 256, 0, stream>>>(Xs, row_ptr, col, dis, Xa, NN);
    gemm128_kernel<1><<<ggrid, 256, 0, stream>>>(Xa, W1t, dis, b1, Hb, NN, FIN);
    // layers 2,3: transform-then-aggregate
    gemm128_kernel<0><<<ggrid, 256, 0, stream>>>(Hb, W2t, dis, b2, Yb, NN, HID);
    agg256_kernel<<<agrid, 256, 0, stream>>>(Yb, row_ptr, col, dis, b2, Hb, NN);
    gemm128_kernel<0><<<ggrid, 256, 0, stream>>>(Hb, W3t, dis, b3, Yb, NN, HID);
    agg256_kernel<<<agrid, 256, 0, stream>>>(Yb, row_ptr, col, dis, b3, Hb, NN);
    pool_mlp_kernel<<<NG, 256, 0, stream>>>(Hb, goff, mol, rings, fcW1, fcb1, fcW2, fcb2, out);
}

// Round 6
// 481.689 us; speedup vs baseline: 2.1476x; 1.0524x over previous
//
#include <hip/hip_runtime.h>

#define NN 50000
#define NE 800000
#define NG 512
#define FIN 128
#define HID 256

typedef short short8 __attribute__((ext_vector_type(8)));
typedef float f32x4 __attribute__((ext_vector_type(4)));

static inline int cdiv(int a, int b) { return (a + b - 1) / b; }

static __device__ inline unsigned short f2bf(float f) {
    unsigned int u = __float_as_uint(f);
    unsigned int r = (u + 0x7FFF + ((u >> 16) & 1)) >> 16;  // RNE
    return (unsigned short)r;
}
static __device__ inline float bf2f(unsigned short h) {
    return __uint_as_float(((unsigned int)h) << 16);
}
static __device__ inline float bflo(unsigned int p) { return __uint_as_float(p << 16); }
static __device__ inline float bfhi(unsigned int p) { return __uint_as_float(p & 0xFFFF0000u); }

typedef __attribute__((address_space(1))) unsigned int gu32;
typedef __attribute__((address_space(3))) unsigned int lu32;
static __device__ __forceinline__ void gload16(const unsigned short* g, unsigned short* l) {
    __builtin_amdgcn_global_load_lds((const gu32*)(const void*)g, (lu32*)(void*)l, 16, 0, 0);
}

// fused histogram: edges -> cnt[dst], nodes -> gcnt[batch]
__global__ void count_all_kernel(const int* __restrict__ dst, const int* __restrict__ batch,
                                 int* __restrict__ cnt, int* __restrict__ gcnt) {
    int i = blockIdx.x * 256 + threadIdx.x;
    if (i < NE) atomicAdd(&cnt[dst[i]], 1);
    else {
        int j = i - NE;
        if (j < NN) atomicAdd(&gcnt[batch[j]], 1);
    }
}

// per-block sum of cnt + dis computation (fused)
__global__ void reduce_dis_kernel(const int* __restrict__ cnt, int* __restrict__ bsum,
                                  float* __restrict__ dis, int n) {
    int i = blockIdx.x * 256 + threadIdx.x;
    int v = (i < n) ? cnt[i] : 0;
    if (i < n) dis[i] = rsqrtf((float)v + 1.0f);
    int s = v;
    #pragma unroll
    for (int off = 32; off; off >>= 1) s += __shfl_down(s, off, 64);
    __shared__ int ws[4];
    if ((threadIdx.x & 63) == 0) ws[threadIdx.x >> 6] = s;
    __syncthreads();
    if (threadIdx.x == 0) bsum[blockIdx.x] = ws[0] + ws[1] + ws[2] + ws[3];
}

// one dispatch, two independent single-block scans:
// block 0: bsum[nb] -> boff[nb+1];  block 1: gcnt[NG] -> goff[NG+1]
__global__ void dual_scan_kernel(const int* __restrict__ bsum, int* __restrict__ boff, int nb,
                                 const int* __restrict__ gcnt, int* __restrict__ goff) {
    const int* in  = (blockIdx.x == 0) ? bsum : gcnt;
    int*       out = (blockIdx.x == 0) ? boff : goff;
    int n          = (blockIdx.x == 0) ? nb : NG;
    __shared__ int wsum[4];
    __shared__ int carry_s;
    int tid = threadIdx.x, lane = tid & 63, wid = tid >> 6;
    if (tid == 0) carry_s = 0;
    __syncthreads();
    for (int base = 0; base < n; base += 256) {
        int i = base + tid;
        int v = (i < n) ? in[i] : 0;
        int incl = v;
        #pragma unroll
        for (int off = 1; off < 64; off <<= 1) {
            int u = __shfl_up(incl, off, 64);
            if (lane >= off) incl += u;
        }
        if (lane == 63) wsum[wid] = incl;
        __syncthreads();
        int woff = 0;
        for (int w = 0; w < wid; ++w) woff += wsum[w];
        int total = wsum[0] + wsum[1] + wsum[2] + wsum[3];
        if (i < n) out[i] = carry_s + woff + incl - v;
        __syncthreads();
        if (tid == 0) carry_s += total;
        __syncthreads();
    }
    if (threadIdx.x == 0) out[n] = carry_s;
}

// local exclusive scan + block offset; also writes cursor copy
__global__ void scan_add_kernel(const int* __restrict__ in, const int* __restrict__ boff,
                                int* __restrict__ out, int* __restrict__ cursor, int n) {
    int b = blockIdx.x, tid = threadIdx.x;
    int i = b * 256 + tid;
    int lane = tid & 63, wid = tid >> 6;
    int v = (i < n) ? in[i] : 0;
    int incl = v;
    #pragma unroll
    for (int off = 1; off < 64; off <<= 1) {
        int u = __shfl_up(incl, off, 64);
        if (lane >= off) incl += u;
    }
    __shared__ int ws[4];
    if (lane == 63) ws[wid] = incl;
    __syncthreads();
    int woff = 0;
    for (int w = 0; w < wid; ++w) woff += ws[w];
    if (i < n) {
        int ex = boff[b] + woff + incl - v;
        out[i] = ex;
        cursor[i] = ex;
    }
    if (b == 0 && tid == 0) out[n] = boff[gridDim.x];
}

__global__ void fill_kernel(const int* __restrict__ src, const int* __restrict__ dst,
                            int* __restrict__ cursor, int* __restrict__ col, int n) {
    int i = blockIdx.x * 256 + threadIdx.x;
    if (i < n) {
        int pos = atomicAdd(&cursor[dst[i]], 1);
        col[pos] = src[i];
    }
}

// Xs[i][f] = bf16(dis[i] * x[i][f])
__global__ void cast_scale_kernel(const float* __restrict__ x, const float* __restrict__ dis,
                                  unsigned short* __restrict__ Xs, int n4) {
    int i = blockIdx.x * 256 + threadIdx.x;
    if (i < n4) {
        float dv = dis[i >> 5];
        float4 v = ((const float4*)x)[i];
        ushort4 o;
        o.x = f2bf(dv * v.x); o.y = f2bf(dv * v.y); o.z = f2bf(dv * v.z); o.w = f2bf(dv * v.w);
        ((ushort4*)Xs)[i] = o;
    }
}

// all three weights transposed+cast in one dispatch.
// W [K,256] fp32 -> Wt [256,K] bf16
__global__ void tcast_all_kernel(const float* __restrict__ W1, const float* __restrict__ W2,
                                 const float* __restrict__ W3,
                                 unsigned short* __restrict__ W1t, unsigned short* __restrict__ W2t,
                                 unsigned short* __restrict__ W3t) {
    int idx = blockIdx.x * 256 + threadIdx.x;
    if (idx < FIN * 256) {
        int n = idx / FIN, k = idx - n * FIN;
        W1t[idx] = f2bf(W1[(size_t)k * 256 + n]);
    } else if (idx < FIN * 256 + HID * 256) {
        int t = idx - FIN * 256;
        int n = t / HID, k = t - n * HID;
        W2t[t] = f2bf(W2[(size_t)k * 256 + n]);
    } else {
        int t = idx - FIN * 256 - HID * 256;
        int n = t / HID, k = t - n * HID;
        W3t[t] = f2bf(W3[(size_t)k * 256 + n]);
    }
}

// 128x128 GEMM, BK=32, global_load_lds staging. A:[M,K] bf16, Bt:[256,K] bf16.
// MODE 0: Hs = bf16(dis[row]*relu(acc + bias[col]))   (feeds next aggregation)
// MODE 1: Hf = bf16(relu(acc + bias[col]))            (final layer, feeds pooling)
template <int MODE>
__global__ __launch_bounds__(256) void gemm128_kernel(
        const unsigned short* __restrict__ A, const unsigned short* __restrict__ Bt,
        const float* __restrict__ dis, const float* __restrict__ bias,
        unsigned short* __restrict__ Cout, int M, int K) {
    __shared__ unsigned short As[128 * 32];   // unpadded (glds lane-contiguous constraint)
    __shared__ unsigned short Bs[128 * 32];
    const int tid = threadIdx.x;
    const int bm = blockIdx.x * 128, bn = blockIdx.y * 128;
    const int wave = tid >> 6, lane = tid & 63;
    const int l16 = lane & 15, quad = lane >> 4;
    const int wm = (wave & 1) * 64, wn = (wave >> 1) * 64;

    int srow0 = tid >> 2, skc = (tid & 3) * 8;
    int srow1 = (256 + tid) >> 2;
    int ar0 = bm + srow0; if (ar0 > M - 1) ar0 = M - 1;
    int ar1 = bm + srow1; if (ar1 > M - 1) ar1 = M - 1;

    f32x4 acc[4][4];
    #pragma unroll
    for (int i = 0; i < 4; ++i)
        #pragma unroll
        for (int j = 0; j < 4; ++j) acc[i][j] = (f32x4){0.f, 0.f, 0.f, 0.f};

    for (int k0 = 0; k0 < K; k0 += 32) {
        gload16(A + (size_t)ar0 * K + k0 + skc, &As[(size_t)tid * 8]);
        gload16(A + (size_t)ar1 * K + k0 + skc, &As[(size_t)(256 + tid) * 8]);
        gload16(Bt + (size_t)(bn + srow0) * K + k0 + skc, &Bs[(size_t)tid * 8]);
        gload16(Bt + (size_t)(bn + srow1) * K + k0 + skc, &Bs[(size_t)(256 + tid) * 8]);
        __syncthreads();
        short8 af[4], bf[4];
        #pragma unroll
        for (int mt = 0; mt < 4; ++mt) af[mt] = *(const short8*)&As[(wm + mt * 16 + l16) * 32 + quad * 8];
        #pragma unroll
        for (int nt = 0; nt < 4; ++nt) bf[nt] = *(const short8*)&Bs[(wn + nt * 16 + l16) * 32 + quad * 8];
        #pragma unroll
        for (int mt = 0; mt < 4; ++mt)
            #pragma unroll
            for (int nt = 0; nt < 4; ++nt)
                acc[mt][nt] = __builtin_amdgcn_mfma_f32_16x16x32_bf16(af[mt], bf[nt], acc[mt][nt], 0, 0, 0);
        __syncthreads();
    }
    // C/D: col = l16 (+16*nt +wn), row = quad*4 + reg (+16*mt +wm)
    float bv[4];
    #pragma unroll
    for (int nt = 0; nt < 4; ++nt) bv[nt] = bias[bn + wn + nt * 16 + l16];
    #pragma unroll
    for (int mt = 0; mt < 4; ++mt) {
        #pragma unroll
        for (int r = 0; r < 4; ++r) {
            int row = bm + wm + mt * 16 + quad * 4 + r;
            if (row < M) {
                unsigned short* crow = Cout + (size_t)row * HID + bn + wn + l16;
                if (MODE == 0) {
                    float dv = dis[row];
                    #pragma unroll
                    for (int nt = 0; nt < 4; ++nt)
                        crow[nt * 16] = f2bf(dv * fmaxf(acc[mt][nt][r] + bv[nt], 0.f));
                } else {
                    #pragma unroll
                    for (int nt = 0; nt < 4; ++nt)
                        crow[nt * 16] = f2bf(fmaxf(acc[mt][nt][r] + bv[nt], 0.f));
                }
            }
        }
    }
}

// layer-1 aggregation over Xs (bf16, 128 feat, 4B/lane): Xa[v] = bf16(dis[v]*(Σ_N Xs[u] + Xs[v]))
__global__ __launch_bounds__(256) void agg128_kernel(
        const unsigned short* __restrict__ Xs, const int* __restrict__ row_ptr,
        const int* __restrict__ col, const float* __restrict__ dis,
        unsigned short* __restrict__ Xa, int n) {
    int node = blockIdx.x * 4 + (threadIdx.x >> 6);
    if (node >= n) return;
    int lane = threadIdx.x & 63;
    const unsigned int* Xv = (const unsigned int*)Xs;
    unsigned int p = Xv[(size_t)node * 64 + lane];  // self loop
    float ax = bflo(p), ay = bfhi(p);
    int e = row_ptr[node], end = row_ptr[node + 1];
    for (; e + 7 < end; e += 8) {
        unsigned int m[8];
        #pragma unroll
        for (int j = 0; j < 8; ++j) m[j] = Xv[(size_t)col[e + j] * 64 + lane];
        #pragma unroll
        for (int j = 0; j < 8; ++j) { ax += bflo(m[j]); ay += bfhi(m[j]); }
    }
    for (; e < end; ++e) {
        unsigned int m = Xv[(size_t)col[e] * 64 + lane];
        ax += bflo(m); ay += bfhi(m);
    }
    float dv = dis[node];
    unsigned int o = (unsigned int)f2bf(dv * ax) | ((unsigned int)f2bf(dv * ay) << 16);
    ((unsigned int*)Xa)[(size_t)node * 64 + lane] = o;
}

// layers 2,3 aggregation over Hs (bf16, 256 feat, 8B/lane):
// G[v] = bf16(dis[v]*(Σ_N Hs[u] + Hs[v]))
__global__ __launch_bounds__(256) void agg256_kernel(
        const unsigned short* __restrict__ Hs, const int* __restrict__ row_ptr,
        const int* __restrict__ col, const float* __restrict__ dis,
        unsigned short* __restrict__ G, int n) {
    int node = blockIdx.x * 4 + (threadIdx.x >> 6);
    if (node >= n) return;
    int lane = threadIdx.x & 63;
    const uint2* Hv = (const uint2*)Hs;
    uint2 p = Hv[(size_t)node * 64 + lane];
    float4 acc = make_float4(bflo(p.x), bfhi(p.x), bflo(p.y), bfhi(p.y));
    int e = row_ptr[node], end = row_ptr[node + 1];
    for (; e + 7 < end; e += 8) {
        uint2 m[8];
        #pragma unroll
        for (int j = 0; j < 8; ++j) m[j] = Hv[(size_t)col[e + j] * 64 + lane];
        #pragma unroll
        for (int j = 0; j < 8; ++j) {
            acc.x += bflo(m[j].x); acc.y += bfhi(m[j].x);
            acc.z += bflo(m[j].y); acc.w += bfhi(m[j].y);
        }
    }
    for (; e < end; ++e) {
        uint2 m = Hv[(size_t)col[e] * 64 + lane];
        acc.x += bflo(m.x); acc.y += bfhi(m.x);
        acc.z += bflo(m.y); acc.w += bfhi(m.y);
    }
    float dv = dis[node];
    ushort4 o;
    o.x = f2bf(dv * acc.x); o.y = f2bf(dv * acc.y);
    o.z = f2bf(dv * acc.z); o.w = f2bf(dv * acc.w);
    ((ushort4*)G)[(size_t)node * 64 + lane] = o;
}

// one block per graph: mean-pool (bf16 Hf) + concat + FC1(relu) + FC2
__global__ __launch_bounds__(256) void pool_mlp_kernel(
        const unsigned short* __restrict__ H, const int* __restrict__ goff,
        const float* __restrict__ mol, const float* __restrict__ rings,
        const float* __restrict__ fcW1, const float* __restrict__ fcb1,
        const float* __restrict__ fcW2, const float* __restrict__ fcb2,
        float* __restrict__ out) {
    __shared__ float s_hg[258];
    __shared__ float s_t[196];
    int g = blockIdx.x, tid = threadIdx.x;
    int beg = goff[g], end = goff[g + 1];
    float acc = 0.f;
    for (int i = beg; i < end; ++i) acc += bf2f(H[(size_t)i * HID + tid]);
    s_hg[tid] = acc / fmaxf((float)(end - beg), 1.0f);
    if (tid == 0) { s_hg[256] = mol[g]; s_hg[257] = rings[g]; }
    __syncthreads();
    if (tid < 196) {
        float a = fcb1[tid];
        for (int k = 0; k < 258; ++k) a = fmaf(s_hg[k], fcW1[k * 196 + tid], a);
        s_t[tid] = fmaxf(a, 0.f);
    }
    __syncthreads();
    if (tid < 16) {
        float a = fcb2[tid];
        for (int k = 0; k < 196; ++k) a = fmaf(s_t[k], fcW2[k * 16 + tid], a);
        out[g * 16 + tid] = a;
    }
}

extern "C" void kernel_launch(void* const* d_in, const int* in_sizes, int n_in,
                              void* d_out, int out_size, void* d_ws, size_t ws_size,
                              hipStream_t stream) {
    const float* x     = (const float*)d_in[0];
    const int*   ei    = (const int*)d_in[1];
    const int*   batch = (const int*)d_in[2];
    const float* mol   = (const float*)d_in[3];
    const float* rings = (const float*)d_in[4];
    const float* W1 = (const float*)d_in[5];
    const float* b1 = (const float*)d_in[6];
    const float* W2 = (const float*)d_in[7];
    const float* b2 = (const float*)d_in[8];
    const float* W3 = (const float*)d_in[9];
    const float* b3 = (const float*)d_in[10];
    const float* fcW1 = (const float*)d_in[11];
    const float* fcb1 = (const float*)d_in[12];
    const float* fcW2 = (const float*)d_in[13];
    const float* fcb2 = (const float*)d_in[14];
    float* out = (float*)d_out;
    const int* src = ei;
    const int* dst = ei + NE;

    char* w = (char*)d_ws;
    auto alloc = [&](size_t bytes) {
        char* p = w;
        w += (bytes + 255) & ~(size_t)255;
        return p;
    };
    int*   cnt     = (int*)alloc((size_t)(NN + NG) * 4);  // cnt[NN] | gcnt[NG] contiguous, one memset
    int*   gcnt    = cnt + NN;
    int*   row_ptr = (int*)alloc((size_t)(NN + 1) * 4);
    int*   cursor  = (int*)alloc((size_t)NN * 4);
    int*   goff    = (int*)alloc((size_t)(NG + 1) * 4);
    int*   bsum    = (int*)alloc((size_t)256 * 4);
    int*   boff    = (int*)alloc((size_t)257 * 4);
    float* dis     = (float*)alloc((size_t)NN * 4);
    int*   col     = (int*)alloc((size_t)NE * 4);
    unsigned short* Xs  = (unsigned short*)alloc((size_t)NN * FIN * 2);
    unsigned short* Xa  = (unsigned short*)alloc((size_t)NN * FIN * 2);
    unsigned short* Hs  = (unsigned short*)alloc((size_t)NN * HID * 2);  // GEMM out, gather operand
    unsigned short* Ga  = (unsigned short*)alloc((size_t)NN * HID * 2);  // aggregated, GEMM in
    unsigned short* Hf  = (unsigned short*)alloc((size_t)NN * HID * 2);  // final layer out
    unsigned short* W1t = (unsigned short*)alloc((size_t)FIN * HID * 2);
    unsigned short* W2t = (unsigned short*)alloc((size_t)HID * HID * 2);
    unsigned short* W3t = (unsigned short*)alloc((size_t)HID * HID * 2);

    hipMemsetAsync(cnt, 0, (size_t)(NN + NG) * 4, stream);
    count_all_kernel<<<cdiv(NE + NN, 256), 256, 0, stream>>>(dst, batch, cnt, gcnt);

    int nb = cdiv(NN, 256);  // 196
    reduce_dis_kernel<<<nb, 256, 0, stream>>>(cnt, bsum, dis, NN);
    dual_scan_kernel<<<2, 256, 0, stream>>>(bsum, boff, nb, gcnt, goff);
    scan_add_kernel<<<nb, 256, 0, stream>>>(cnt, boff, row_ptr, cursor, NN);
    fill_kernel<<<cdiv(NE, 256), 256, 0, stream>>>(src, dst, cursor, col, NE);

    cast_scale_kernel<<<cdiv(NN * FIN / 4, 256), 256, 0, stream>>>(x, dis, Xs, NN * FIN / 4);
    tcast_all_kernel<<<cdiv((FIN + HID + HID) * 256, 256), 256, 0, stream>>>(W1, W2, W3, W1t, W2t, W3t);

    dim3 ggrid(cdiv(NN, 128), 2);
    int agrid = cdiv(NN, 4);
    // all layers: aggregate-then-transform (aggregation commutes with @W)
    agg128_kernel<<<agrid, 256, 0, stream>>>(Xs, row_ptr, col, dis, Xa, NN);
    gemm128_kernel<0><<<ggrid, 256, 0, stream>>>(Xa, W1t, dis, b1, Hs, NN, FIN);  // Hs1 = bf16(dis*relu)
    agg256_kernel<<<agrid, 256, 0, stream>>>(Hs, row_ptr, col, dis, Ga, NN);       // Ga2
    gemm128_kernel<0><<<ggrid, 256, 0, stream>>>(Ga, W2t, dis, b2, Hs, NN, HID);  // Hs2
    agg256_kernel<<<agrid, 256, 0, stream>>>(Hs, row_ptr, col, dis, Ga, NN);       // Ga3
    gemm128_kernel<1><<<ggrid, 256, 0, stream>>>(Ga, W3t, dis, b3, Hf, NN, HID);  // Hf = bf16(relu)
    pool_mlp_kernel<<<NG, 256, 0, stream>>>(Hf, goff, mol, rings, fcW1, fcb1, fcW2, fcb2, out);
}

// Round 7
// 406.477 us; speedup vs baseline: 2.5450x; 1.1850x over previous
//
#include <hip/hip_runtime.h>

#define NN 50000
#define NE 800000
#define NG 512
#define FIN 128
#define HID 256
#define NBUK 196   // buckets of 256 node ids: ceil(50000/256)

typedef short short8 __attribute__((ext_vector_type(8)));
typedef float f32x4 __attribute__((ext_vector_type(4)));

static inline int cdiv(int a, int b) { return (a + b - 1) / b; }

static __device__ inline unsigned short f2bf(float f) {
    unsigned int u = __float_as_uint(f);
    unsigned int r = (u + 0x7FFF + ((u >> 16) & 1)) >> 16;  // RNE
    return (unsigned short)r;
}
static __device__ inline float bf2f(unsigned short h) {
    return __uint_as_float(((unsigned int)h) << 16);
}
static __device__ inline float bflo(unsigned int p) { return __uint_as_float(p << 16); }
static __device__ inline float bfhi(unsigned int p) { return __uint_as_float(p & 0xFFFF0000u); }

typedef __attribute__((address_space(1))) unsigned int gu32;
typedef __attribute__((address_space(3))) unsigned int lu32;
static __device__ __forceinline__ void gload16(const unsigned short* g, unsigned short* l) {
    __builtin_amdgcn_global_load_lds((const gu32*)(const void*)g, (lu32*)(void*)l, 16, 0, 0);
}

// ---- CSR build, bucket-sort style (no per-edge global atomics) ----

// coarse 196-bucket histogram of dst, LDS-privatized
__global__ __launch_bounds__(256) void hist_bucket_kernel(const int* __restrict__ dst,
                                                          int* __restrict__ gbuk) {
    __shared__ int lh[NBUK];
    int tid = threadIdx.x;
    for (int j = tid; j < NBUK; j += 256) lh[j] = 0;
    __syncthreads();
    int base = blockIdx.x * 2048;
    #pragma unroll
    for (int k = 0; k < 8; ++k) {
        int i = base + k * 256 + tid;
        if (i < NE) atomicAdd(&lh[dst[i] >> 8], 1);
    }
    __syncthreads();
    for (int j = tid; j < NBUK; j += 256) if (lh[j]) atomicAdd(&gbuk[j], lh[j]);
}

// batch is sorted: goff by boundary detection, no atomics
__global__ void goff_kernel(const int* __restrict__ batch, int* __restrict__ goff) {
    int i = blockIdx.x * 256 + threadIdx.x;
    if (i >= NN) return;
    int b = batch[i];
    int pb = (i == 0) ? -1 : batch[i - 1];
    for (int g = pb + 1; g <= b; ++g) goff[g] = i;
    if (i == NN - 1) for (int g = b + 1; g <= NG; ++g) goff[g] = NN;
}

// single-block exclusive scan of gbuk[196] -> bukoff[197], plus cursor copy
__global__ void buk_scan_kernel(const int* __restrict__ gbuk, int* __restrict__ bukoff,
                                int* __restrict__ bukcur) {
    __shared__ int ws[4];
    int tid = threadIdx.x, lane = tid & 63, wid = tid >> 6;
    int v = (tid < NBUK) ? gbuk[tid] : 0;
    int incl = v;
    #pragma unroll
    for (int off = 1; off < 64; off <<= 1) {
        int u = __shfl_up(incl, off, 64);
        if (lane >= off) incl += u;
    }
    if (lane == 63) ws[wid] = incl;
    __syncthreads();
    int woff = 0;
    for (int w = 0; w < wid; ++w) woff += ws[w];
    int ex = woff + incl - v;
    if (tid < NBUK) { bukoff[tid] = ex; bukcur[tid] = ex; }
    if (tid == NBUK - 1) bukoff[NBUK] = ex + v;
}

// scatter edges into bucket-contiguous pairs[]; one global atomic per block per bucket
__global__ __launch_bounds__(256) void scatter_kernel(const int* __restrict__ src,
                                                      const int* __restrict__ dst,
                                                      int* __restrict__ bukcur,
                                                      unsigned int* __restrict__ pairs) {
    __shared__ int lh[NBUK];
    __shared__ int lbase[NBUK];
    int tid = threadIdx.x;
    for (int j = tid; j < NBUK; j += 256) lh[j] = 0;
    __syncthreads();
    int base = blockIdx.x * 2048;
    int d[8], s[8];
    #pragma unroll
    for (int k = 0; k < 8; ++k) {
        int i = base + k * 256 + tid;
        if (i < NE) {
            d[k] = dst[i]; s[k] = src[i];
            atomicAdd(&lh[d[k] >> 8], 1);
        } else d[k] = -1;
    }
    __syncthreads();
    for (int j = tid; j < NBUK; j += 256) lbase[j] = lh[j] ? atomicAdd(&bukcur[j], lh[j]) : 0;
    __syncthreads();
    for (int j = tid; j < NBUK; j += 256) lh[j] = 0;
    __syncthreads();
    #pragma unroll
    for (int k = 0; k < 8; ++k) {
        if (d[k] >= 0) {
            int b = d[k] >> 8;
            int loc = atomicAdd(&lh[b], 1);
            pairs[lbase[b] + loc] = ((unsigned int)s[k] << 16) | (unsigned int)(d[k] & 255);
        }
    }
}

// per-bucket fine CSR: row_ptr, col, dis (one block per bucket)
__global__ __launch_bounds__(256) void local_csr_kernel(const unsigned int* __restrict__ pairs,
                                                        const int* __restrict__ bukoff,
                                                        int* __restrict__ row_ptr,
                                                        int* __restrict__ col,
                                                        float* __restrict__ dis) {
    __shared__ int fcnt[256];
    __shared__ int foff[256];
    __shared__ int fws[4];
    int b = blockIdx.x, tid = threadIdx.x;
    int beg = bukoff[b], end = bukoff[b + 1];
    fcnt[tid] = 0;
    __syncthreads();
    for (int i = beg + tid; i < end; i += 256) atomicAdd(&fcnt[pairs[i] & 255], 1);
    __syncthreads();
    int lane = tid & 63, wid = tid >> 6;
    int v = fcnt[tid], incl = v;
    #pragma unroll
    for (int off = 1; off < 64; off <<= 1) {
        int u = __shfl_up(incl, off, 64);
        if (lane >= off) incl += u;
    }
    if (lane == 63) fws[wid] = incl;
    __syncthreads();
    int woff = 0;
    for (int w = 0; w < wid; ++w) woff += fws[w];
    int ex = woff + incl - v;  // exclusive fine offset
    foff[tid] = ex;
    int gid = b * 256 + tid;
    if (gid < NN) {
        row_ptr[gid] = beg + ex;
        dis[gid] = rsqrtf((float)v + 1.0f);
    }
    if (b == 0 && tid == 0) row_ptr[NN] = NE;
    __syncthreads();
    // scatter src into col using foff as LDS cursors
    for (int i = beg + tid; i < end; i += 256) {
        unsigned int p = pairs[i];
        int loc = atomicAdd(&foff[p & 255], 1);
        col[beg + loc] = (int)(p >> 16);
    }
}

// Xs[i][f] = bf16(dis[i] * x[i][f])
__global__ void cast_scale_kernel(const float* __restrict__ x, const float* __restrict__ dis,
                                  unsigned short* __restrict__ Xs, int n4) {
    int i = blockIdx.x * 256 + threadIdx.x;
    if (i < n4) {
        float dv = dis[i >> 5];
        float4 v = ((const float4*)x)[i];
        ushort4 o;
        o.x = f2bf(dv * v.x); o.y = f2bf(dv * v.y); o.z = f2bf(dv * v.z); o.w = f2bf(dv * v.w);
        ((ushort4*)Xs)[i] = o;
    }
}

// all three weights transposed+cast in one dispatch: W [K,256] fp32 -> Wt [256,K] bf16
__global__ void tcast_all_kernel(const float* __restrict__ W1, const float* __restrict__ W2,
                                 const float* __restrict__ W3,
                                 unsigned short* __restrict__ W1t, unsigned short* __restrict__ W2t,
                                 unsigned short* __restrict__ W3t) {
    int idx = blockIdx.x * 256 + threadIdx.x;
    if (idx < FIN * 256) {
        int n = idx / FIN, k = idx - n * FIN;
        W1t[idx] = f2bf(W1[(size_t)k * 256 + n]);
    } else if (idx < FIN * 256 + HID * 256) {
        int t = idx - FIN * 256;
        int n = t / HID, k = t - n * HID;
        W2t[t] = f2bf(W2[(size_t)k * 256 + n]);
    } else {
        int t = idx - FIN * 256 - HID * 256;
        int n = t / HID, k = t - n * HID;
        W3t[t] = f2bf(W3[(size_t)k * 256 + n]);
    }
}

// 128x128 GEMM, BK=32, global_load_lds staging. A:[M,K] bf16, Bt:[256,K] bf16.
// MODE 0: Hs = bf16(dis[row]*relu(acc + bias[col]))   (feeds next aggregation)
// MODE 1: Hf = bf16(relu(acc + bias[col]))            (final layer, feeds pooling)
template <int MODE>
__global__ __launch_bounds__(256) void gemm128_kernel(
        const unsigned short* __restrict__ A, const unsigned short* __restrict__ Bt,
        const float* __restrict__ dis, const float* __restrict__ bias,
        unsigned short* __restrict__ Cout, int M, int K) {
    __shared__ unsigned short As[128 * 32];   // unpadded (glds lane-contiguous constraint)
    __shared__ unsigned short Bs[128 * 32];
    const int tid = threadIdx.x;
    const int bm = blockIdx.x * 128, bn = blockIdx.y * 128;
    const int wave = tid >> 6, lane = tid & 63;
    const int l16 = lane & 15, quad = lane >> 4;
    const int wm = (wave & 1) * 64, wn = (wave >> 1) * 64;

    int srow0 = tid >> 2, skc = (tid & 3) * 8;
    int srow1 = (256 + tid) >> 2;
    int ar0 = bm + srow0; if (ar0 > M - 1) ar0 = M - 1;
    int ar1 = bm + srow1; if (ar1 > M - 1) ar1 = M - 1;

    f32x4 acc[4][4];
    #pragma unroll
    for (int i = 0; i < 4; ++i)
        #pragma unroll
        for (int j = 0; j < 4; ++j) acc[i][j] = (f32x4){0.f, 0.f, 0.f, 0.f};

    for (int k0 = 0; k0 < K; k0 += 32) {
        gload16(A + (size_t)ar0 * K + k0 + skc, &As[(size_t)tid * 8]);
        gload16(A + (size_t)ar1 * K + k0 + skc, &As[(size_t)(256 + tid) * 8]);
        gload16(Bt + (size_t)(bn + srow0) * K + k0 + skc, &Bs[(size_t)tid * 8]);
        gload16(Bt + (size_t)(bn + srow1) * K + k0 + skc, &Bs[(size_t)(256 + tid) * 8]);
        __syncthreads();
        short8 af[4], bf[4];
        #pragma unroll
        for (int mt = 0; mt < 4; ++mt) af[mt] = *(const short8*)&As[(wm + mt * 16 + l16) * 32 + quad * 8];
        #pragma unroll
        for (int nt = 0; nt < 4; ++nt) bf[nt] = *(const short8*)&Bs[(wn + nt * 16 + l16) * 32 + quad * 8];
        #pragma unroll
        for (int mt = 0; mt < 4; ++mt)
            #pragma unroll
            for (int nt = 0; nt < 4; ++nt)
                acc[mt][nt] = __builtin_amdgcn_mfma_f32_16x16x32_bf16(af[mt], bf[nt], acc[mt][nt], 0, 0, 0);
        __syncthreads();
    }
    float bv[4];
    #pragma unroll
    for (int nt = 0; nt < 4; ++nt) bv[nt] = bias[bn + wn + nt * 16 + l16];
    #pragma unroll
    for (int mt = 0; mt < 4; ++mt) {
        #pragma unroll
        for (int r = 0; r < 4; ++r) {
            int row = bm + wm + mt * 16 + quad * 4 + r;
            if (row < M) {
                unsigned short* crow = Cout + (size_t)row * HID + bn + wn + l16;
                if (MODE == 0) {
                    float dv = dis[row];
                    #pragma unroll
                    for (int nt = 0; nt < 4; ++nt)
                        crow[nt * 16] = f2bf(dv * fmaxf(acc[mt][nt][r] + bv[nt], 0.f));
                } else {
                    #pragma unroll
                    for (int nt = 0; nt < 4; ++nt)
                        crow[nt * 16] = f2bf(fmaxf(acc[mt][nt][r] + bv[nt], 0.f));
                }
            }
        }
    }
}

// layer-1 aggregation over Xs (bf16, 128 feat, 4B/lane): Xa[v] = bf16(dis[v]*(Σ_N Xs[u] + Xs[v]))
__global__ __launch_bounds__(256) void agg128_kernel(
        const unsigned short* __restrict__ Xs, const int* __restrict__ row_ptr,
        const int* __restrict__ col, const float* __restrict__ dis,
        unsigned short* __restrict__ Xa, int n) {
    int node = blockIdx.x * 4 + (threadIdx.x >> 6);
    if (node >= n) return;
    int lane = threadIdx.x & 63;
    const unsigned int* Xv = (const unsigned int*)Xs;
    unsigned int p = Xv[(size_t)node * 64 + lane];  // self loop
    float ax = bflo(p), ay = bfhi(p);
    int e = row_ptr[node], end = row_ptr[node + 1];
    for (; e + 7 < end; e += 8) {
        unsigned int m[8];
        #pragma unroll
        for (int j = 0; j < 8; ++j) m[j] = Xv[(size_t)col[e + j] * 64 + lane];
        #pragma unroll
        for (int j = 0; j < 8; ++j) { ax += bflo(m[j]); ay += bfhi(m[j]); }
    }
    for (; e < end; ++e) {
        unsigned int m = Xv[(size_t)col[e] * 64 + lane];
        ax += bflo(m); ay += bfhi(m);
    }
    float dv = dis[node];
    unsigned int o = (unsigned int)f2bf(dv * ax) | ((unsigned int)f2bf(dv * ay) << 16);
    ((unsigned int*)Xa)[(size_t)node * 64 + lane] = o;
}

// layers 2,3 aggregation over Hs (bf16, 256 feat, 8B/lane): G[v] = bf16(dis[v]*(Σ_N Hs[u] + Hs[v]))
__global__ __launch_bounds__(256) void agg256_kernel(
        const unsigned short* __restrict__ Hs, const int* __restrict__ row_ptr,
        const int* __restrict__ col, const float* __restrict__ dis,
        unsigned short* __restrict__ G, int n) {
    int node = blockIdx.x * 4 + (threadIdx.x >> 6);
    if (node >= n) return;
    int lane = threadIdx.x & 63;
    const uint2* Hv = (const uint2*)Hs;
    uint2 p = Hv[(size_t)node * 64 + lane];
    float4 acc = make_float4(bflo(p.x), bfhi(p.x), bflo(p.y), bfhi(p.y));
    int e = row_ptr[node], end = row_ptr[node + 1];
    for (; e + 7 < end; e += 8) {
        uint2 m[8];
        #pragma unroll
        for (int j = 0; j < 8; ++j) m[j] = Hv[(size_t)col[e + j] * 64 + lane];
        #pragma unroll
        for (int j = 0; j < 8; ++j) {
            acc.x += bflo(m[j].x); acc.y += bfhi(m[j].x);
            acc.z += bflo(m[j].y); acc.w += bfhi(m[j].y);
        }
    }
    for (; e < end; ++e) {
        uint2 m = Hv[(size_t)col[e] * 64 + lane];
        acc.x += bflo(m.x); acc.y += bfhi(m.x);
        acc.z += bflo(m.y); acc.w += bfhi(m.y);
    }
    float dv = dis[node];
    ushort4 o;
    o.x = f2bf(dv * acc.x); o.y = f2bf(dv * acc.y);
    o.z = f2bf(dv * acc.z); o.w = f2bf(dv * acc.w);
    ((ushort4*)G)[(size_t)node * 64 + lane] = o;
}

// one block per graph: mean-pool (bf16 Hf) + concat + FC1(relu) + FC2
__global__ __launch_bounds__(256) void pool_mlp_kernel(
        const unsigned short* __restrict__ H, const int* __restrict__ goff,
        const float* __restrict__ mol, const float* __restrict__ rings,
        const float* __restrict__ fcW1, const float* __restrict__ fcb1,
        const float* __restrict__ fcW2, const float* __restrict__ fcb2,
        float* __restrict__ out) {
    __shared__ float s_hg[258];
    __shared__ float s_t[196];
    int g = blockIdx.x, tid = threadIdx.x;
    int beg = goff[g], end = goff[g + 1];
    float acc = 0.f;
    for (int i = beg; i < end; ++i) acc += bf2f(H[(size_t)i * HID + tid]);
    s_hg[tid] = acc / fmaxf((float)(end - beg), 1.0f);
    if (tid == 0) { s_hg[256] = mol[g]; s_hg[257] = rings[g]; }
    __syncthreads();
    if (tid < 196) {
        float a = fcb1[tid];
        for (int k = 0; k < 258; ++k) a = fmaf(s_hg[k], fcW1[k * 196 + tid], a);
        s_t[tid] = fmaxf(a, 0.f);
    }
    __syncthreads();
    if (tid < 16) {
        float a = fcb2[tid];
        for (int k = 0; k < 196; ++k) a = fmaf(s_t[k], fcW2[k * 16 + tid], a);
        out[g * 16 + tid] = a;
    }
}

extern "C" void kernel_launch(void* const* d_in, const int* in_sizes, int n_in,
                              void* d_out, int out_size, void* d_ws, size_t ws_size,
                              hipStream_t stream) {
    const float* x     = (const float*)d_in[0];
    const int*   ei    = (const int*)d_in[1];
    const int*   batch = (const int*)d_in[2];
    const float* mol   = (const float*)d_in[3];
    const float* rings = (const float*)d_in[4];
    const float* W1 = (const float*)d_in[5];
    const float* b1 = (const float*)d_in[6];
    const float* W2 = (const float*)d_in[7];
    const float* b2 = (const float*)d_in[8];
    const float* W3 = (const float*)d_in[9];
    const float* b3 = (const float*)d_in[10];
    const float* fcW1 = (const float*)d_in[11];
    const float* fcb1 = (const float*)d_in[12];
    const float* fcW2 = (const float*)d_in[13];
    const float* fcb2 = (const float*)d_in[14];
    float* out = (float*)d_out;
    const int* src = ei;
    const int* dst = ei + NE;

    char* w = (char*)d_ws;
    auto alloc = [&](size_t bytes) {
        char* p = w;
        w += (bytes + 255) & ~(size_t)255;
        return p;
    };
    int*   gbuk    = (int*)alloc((size_t)NBUK * 4);
    int*   bukoff  = (int*)alloc((size_t)(NBUK + 1) * 4);
    int*   bukcur  = (int*)alloc((size_t)NBUK * 4);
    int*   row_ptr = (int*)alloc((size_t)(NN + 1) * 4);
    int*   goff    = (int*)alloc((size_t)(NG + 1) * 4);
    float* dis     = (float*)alloc((size_t)NN * 4);
    unsigned int* pairs = (unsigned int*)alloc((size_t)NE * 4);
    int*   col     = (int*)alloc((size_t)NE * 4);
    unsigned short* Xs  = (unsigned short*)alloc((size_t)NN * FIN * 2);
    unsigned short* Xa  = (unsigned short*)alloc((size_t)NN * FIN * 2);
    unsigned short* Hs  = (unsigned short*)alloc((size_t)NN * HID * 2);
    unsigned short* Ga  = (unsigned short*)alloc((size_t)NN * HID * 2);
    unsigned short* Hf  = (unsigned short*)alloc((size_t)NN * HID * 2);
    unsigned short* W1t = (unsigned short*)alloc((size_t)FIN * HID * 2);
    unsigned short* W2t = (unsigned short*)alloc((size_t)HID * HID * 2);
    unsigned short* W3t = (unsigned short*)alloc((size_t)HID * HID * 2);

    hipMemsetAsync(gbuk, 0, (size_t)NBUK * 4, stream);
    int eb = cdiv(NE, 2048);  // 391
    hist_bucket_kernel<<<eb, 256, 0, stream>>>(dst, gbuk);
    goff_kernel<<<cdiv(NN, 256), 256, 0, stream>>>(batch, goff);
    buk_scan_kernel<<<1, 256, 0, stream>>>(gbuk, bukoff, bukcur);
    scatter_kernel<<<eb, 256, 0, stream>>>(src, dst, bukcur, pairs);
    local_csr_kernel<<<NBUK, 256, 0, stream>>>(pairs, bukoff, row_ptr, col, dis);

    cast_scale_kernel<<<cdiv(NN * FIN / 4, 256), 256, 0, stream>>>(x, dis, Xs, NN * FIN / 4);
    tcast_all_kernel<<<cdiv((FIN + HID + HID) * 256, 256), 256, 0, stream>>>(W1, W2, W3, W1t, W2t, W3t);

    dim3 ggrid(cdiv(NN, 128), 2);
    int agrid = cdiv(NN, 4);
    // all layers: aggregate-then-transform (aggregation commutes with @W)
    agg128_kernel<<<agrid, 256, 0, stream>>>(Xs, row_ptr, col, dis, Xa, NN);
    gemm128_kernel<0><<<ggrid, 256, 0, stream>>>(Xa, W1t, dis, b1, Hs, NN, FIN);  // Hs1 = bf16(dis*relu)
    agg256_kernel<<<agrid, 256, 0, stream>>>(Hs, row_ptr, col, dis, Ga, NN);       // Ga2
    gemm128_kernel<0><<<ggrid, 256, 0, stream>>>(Ga, W2t, dis, b2, Hs, NN, HID);  // Hs2
    agg256_kernel<<<agrid, 256, 0, stream>>>(Hs, row_ptr, col, dis, Ga, NN);       // Ga3
    gemm128_kernel<1><<<ggrid, 256, 0, stream>>>(Ga, W3t, dis, b3, Hf, NN, HID);  // Hf = bf16(relu)
    pool_mlp_kernel<<<NG, 256, 0, stream>>>(Hf, goff, mol, rings, fcW1, fcb1, fcW2, fcb2, out);
}

// Round 8
// 402.515 us; speedup vs baseline: 2.5700x; 1.0098x over previous
//
#include <hip/hip_runtime.h>

#define NN 50000
#define NE 800000
#define NG 512
#define FIN 128
#define HID 256
#define NBUK 196   // buckets of 256 node ids: ceil(50000/256)

typedef short short8 __attribute__((ext_vector_type(8)));
typedef float f32x4 __attribute__((ext_vector_type(4)));
typedef unsigned short u16x8 __attribute__((ext_vector_type(8)));

static inline int cdiv(int a, int b) { return (a + b - 1) / b; }

static __device__ inline unsigned short f2bf(float f) {
    unsigned int u = __float_as_uint(f);
    unsigned int r = (u + 0x7FFF + ((u >> 16) & 1)) >> 16;  // RNE
    return (unsigned short)r;
}
static __device__ inline float bf2f(unsigned short h) {
    return __uint_as_float(((unsigned int)h) << 16);
}
static __device__ inline float bflo(unsigned int p) { return __uint_as_float(p << 16); }
static __device__ inline float bfhi(unsigned int p) { return __uint_as_float(p & 0xFFFF0000u); }

typedef __attribute__((address_space(1))) unsigned int gu32;
typedef __attribute__((address_space(3))) unsigned int lu32;
static __device__ __forceinline__ void gload16(const unsigned short* g, unsigned short* l) {
    __builtin_amdgcn_global_load_lds((const gu32*)(const void*)g, (lu32*)(void*)l, 16, 0, 0);
}

// ---- CSR build, bucket-sort style (no per-edge global atomics) ----

// coarse 196-bucket histogram of dst, LDS-privatized
__global__ __launch_bounds__(256) void hist_bucket_kernel(const int* __restrict__ dst,
                                                          int* __restrict__ gbuk) {
    __shared__ int lh[NBUK];
    int tid = threadIdx.x;
    for (int j = tid; j < NBUK; j += 256) lh[j] = 0;
    __syncthreads();
    int base = blockIdx.x * 2048;
    #pragma unroll
    for (int k = 0; k < 8; ++k) {
        int i = base + k * 256 + tid;
        if (i < NE) atomicAdd(&lh[dst[i] >> 8], 1);
    }
    __syncthreads();
    for (int j = tid; j < NBUK; j += 256) if (lh[j]) atomicAdd(&gbuk[j], lh[j]);
}

// batch is sorted: goff by boundary detection, no atomics
__global__ void goff_kernel(const int* __restrict__ batch, int* __restrict__ goff) {
    int i = blockIdx.x * 256 + threadIdx.x;
    if (i >= NN) return;
    int b = batch[i];
    int pb = (i == 0) ? -1 : batch[i - 1];
    for (int g = pb + 1; g <= b; ++g) goff[g] = i;
    if (i == NN - 1) for (int g = b + 1; g <= NG; ++g) goff[g] = NN;
}

// single-block exclusive scan of gbuk[196] -> bukoff[197], plus cursor copy
__global__ void buk_scan_kernel(const int* __restrict__ gbuk, int* __restrict__ bukoff,
                                int* __restrict__ bukcur) {
    __shared__ int ws[4];
    int tid = threadIdx.x, lane = tid & 63, wid = tid >> 6;
    int v = (tid < NBUK) ? gbuk[tid] : 0;
    int incl = v;
    #pragma unroll
    for (int off = 1; off < 64; off <<= 1) {
        int u = __shfl_up(incl, off, 64);
        if (lane >= off) incl += u;
    }
    if (lane == 63) ws[wid] = incl;
    __syncthreads();
    int woff = 0;
    for (int w = 0; w < wid; ++w) woff += ws[w];
    int ex = woff + incl - v;
    if (tid < NBUK) { bukoff[tid] = ex; bukcur[tid] = ex; }
    if (tid == NBUK - 1) bukoff[NBUK] = ex + v;
}

// scatter edges into bucket-contiguous pairs[]; one global atomic per block per bucket
__global__ __launch_bounds__(256) void scatter_kernel(const int* __restrict__ src,
                                                      const int* __restrict__ dst,
                                                      int* __restrict__ bukcur,
                                                      unsigned int* __restrict__ pairs) {
    __shared__ int lh[NBUK];
    __shared__ int lbase[NBUK];
    int tid = threadIdx.x;
    for (int j = tid; j < NBUK; j += 256) lh[j] = 0;
    __syncthreads();
    int base = blockIdx.x * 2048;
    int d[8], s[8];
    #pragma unroll
    for (int k = 0; k < 8; ++k) {
        int i = base + k * 256 + tid;
        if (i < NE) {
            d[k] = dst[i]; s[k] = src[i];
            atomicAdd(&lh[d[k] >> 8], 1);
        } else d[k] = -1;
    }
    __syncthreads();
    for (int j = tid; j < NBUK; j += 256) lbase[j] = lh[j] ? atomicAdd(&bukcur[j], lh[j]) : 0;
    __syncthreads();
    for (int j = tid; j < NBUK; j += 256) lh[j] = 0;
    __syncthreads();
    #pragma unroll
    for (int k = 0; k < 8; ++k) {
        if (d[k] >= 0) {
            int b = d[k] >> 8;
            int loc = atomicAdd(&lh[b], 1);
            pairs[lbase[b] + loc] = ((unsigned int)s[k] << 16) | (unsigned int)(d[k] & 255);
        }
    }
}

// per-bucket fine CSR: row_ptr, col, dis (one block per bucket)
__global__ __launch_bounds__(256) void local_csr_kernel(const unsigned int* __restrict__ pairs,
                                                        const int* __restrict__ bukoff,
                                                        int* __restrict__ row_ptr,
                                                        int* __restrict__ col,
                                                        float* __restrict__ dis) {
    __shared__ int fcnt[256];
    __shared__ int foff[256];
    __shared__ int fws[4];
    int b = blockIdx.x, tid = threadIdx.x;
    int beg = bukoff[b], end = bukoff[b + 1];
    fcnt[tid] = 0;
    __syncthreads();
    for (int i = beg + tid; i < end; i += 256) atomicAdd(&fcnt[pairs[i] & 255], 1);
    __syncthreads();
    int lane = tid & 63, wid = tid >> 6;
    int v = fcnt[tid], incl = v;
    #pragma unroll
    for (int off = 1; off < 64; off <<= 1) {
        int u = __shfl_up(incl, off, 64);
        if (lane >= off) incl += u;
    }
    if (lane == 63) fws[wid] = incl;
    __syncthreads();
    int woff = 0;
    for (int w = 0; w < wid; ++w) woff += fws[w];
    int ex = woff + incl - v;  // exclusive fine offset
    foff[tid] = ex;
    int gid = b * 256 + tid;
    if (gid < NN) {
        row_ptr[gid] = beg + ex;
        dis[gid] = rsqrtf((float)v + 1.0f);
    }
    if (b == 0 && tid == 0) row_ptr[NN] = NE;
    __syncthreads();
    // scatter src into col using foff as LDS cursors
    for (int i = beg + tid; i < end; i += 256) {
        unsigned int p = pairs[i];
        int loc = atomicAdd(&foff[p & 255], 1);
        col[beg + loc] = (int)(p >> 16);
    }
}

// Xs[i][f] = bf16(dis[i] * x[i][f])
__global__ void cast_scale_kernel(const float* __restrict__ x, const float* __restrict__ dis,
                                  unsigned short* __restrict__ Xs, int n4) {
    int i = blockIdx.x * 256 + threadIdx.x;
    if (i < n4) {
        float dv = dis[i >> 5];
        float4 v = ((const float4*)x)[i];
        ushort4 o;
        o.x = f2bf(dv * v.x); o.y = f2bf(dv * v.y); o.z = f2bf(dv * v.z); o.w = f2bf(dv * v.w);
        ((ushort4*)Xs)[i] = o;
    }
}

// all three weights transposed+cast in one dispatch: W [K,256] fp32 -> Wt [256,K] bf16
__global__ void tcast_all_kernel(const float* __restrict__ W1, const float* __restrict__ W2,
                                 const float* __restrict__ W3,
                                 unsigned short* __restrict__ W1t, unsigned short* __restrict__ W2t,
                                 unsigned short* __restrict__ W3t) {
    int idx = blockIdx.x * 256 + threadIdx.x;
    if (idx < FIN * 256) {
        int n = idx / FIN, k = idx - n * FIN;
        W1t[idx] = f2bf(W1[(size_t)k * 256 + n]);
    } else if (idx < FIN * 256 + HID * 256) {
        int t = idx - FIN * 256;
        int n = t / HID, k = t - n * HID;
        W2t[t] = f2bf(W2[(size_t)k * 256 + n]);
    } else {
        int t = idx - FIN * 256 - HID * 256;
        int n = t / HID, k = t - n * HID;
        W3t[t] = f2bf(W3[(size_t)k * 256 + n]);
    }
}

// 128x128 GEMM, BK=32, global_load_lds staging, LDS-bounce coalesced epilogue.
// A:[M,K] bf16, Bt:[256,K] bf16.
// MODE 0: Hs = bf16(dis[row]*relu(acc + bias[col]))   (feeds next aggregation)
// MODE 1: Hf = bf16(relu(acc + bias[col]))            (final layer, feeds pooling)
#define CLD 136   // C-tile LDS row stride in shorts (mult of 8 -> 16B-aligned rows)
template <int MODE>
__global__ __launch_bounds__(256) void gemm128_kernel(
        const unsigned short* __restrict__ A, const unsigned short* __restrict__ Bt,
        const float* __restrict__ dis, const float* __restrict__ bias,
        unsigned short* __restrict__ Cout, int M, int K) {
    __shared__ unsigned short smem[128 * CLD];  // K-loop: As=smem[0:4096], Bs=smem[4096:8192]
    unsigned short* As = smem;
    unsigned short* Bs = smem + 4096;
    const int tid = threadIdx.x;
    const int bm = blockIdx.x * 128, bn = blockIdx.y * 128;
    const int wave = tid >> 6, lane = tid & 63;
    const int l16 = lane & 15, quad = lane >> 4;
    const int wm = (wave & 1) * 64, wn = (wave >> 1) * 64;

    int srow0 = tid >> 2, skc = (tid & 3) * 8;
    int srow1 = (256 + tid) >> 2;
    int ar0 = bm + srow0; if (ar0 > M - 1) ar0 = M - 1;
    int ar1 = bm + srow1; if (ar1 > M - 1) ar1 = M - 1;

    f32x4 acc[4][4];
    #pragma unroll
    for (int i = 0; i < 4; ++i)
        #pragma unroll
        for (int j = 0; j < 4; ++j) acc[i][j] = (f32x4){0.f, 0.f, 0.f, 0.f};

    for (int k0 = 0; k0 < K; k0 += 32) {
        gload16(A + (size_t)ar0 * K + k0 + skc, &As[(size_t)tid * 8]);
        gload16(A + (size_t)ar1 * K + k0 + skc, &As[(size_t)(256 + tid) * 8]);
        gload16(Bt + (size_t)(bn + srow0) * K + k0 + skc, &Bs[(size_t)tid * 8]);
        gload16(Bt + (size_t)(bn + srow1) * K + k0 + skc, &Bs[(size_t)(256 + tid) * 8]);
        __syncthreads();
        short8 af[4], bf[4];
        #pragma unroll
        for (int mt = 0; mt < 4; ++mt) af[mt] = *(const short8*)&As[(wm + mt * 16 + l16) * 32 + quad * 8];
        #pragma unroll
        for (int nt = 0; nt < 4; ++nt) bf[nt] = *(const short8*)&Bs[(wn + nt * 16 + l16) * 32 + quad * 8];
        #pragma unroll
        for (int mt = 0; mt < 4; ++mt)
            #pragma unroll
            for (int nt = 0; nt < 4; ++nt)
                acc[mt][nt] = __builtin_amdgcn_mfma_f32_16x16x32_bf16(af[mt], bf[nt], acc[mt][nt], 0, 0, 0);
        __syncthreads();
    }
    // phase 1: acc -> LDS tile (bf16), bias/relu/dis applied.  C/D: col=l16+16nt+wn, row=quad*4+r+16mt+wm
    float bv[4];
    #pragma unroll
    for (int nt = 0; nt < 4; ++nt) bv[nt] = bias[bn + wn + nt * 16 + l16];
    #pragma unroll
    for (int mt = 0; mt < 4; ++mt) {
        #pragma unroll
        for (int r = 0; r < 4; ++r) {
            int lrow = wm + mt * 16 + quad * 4 + r;
            int grow = bm + lrow; if (grow > M - 1) grow = M - 1;
            float dv = (MODE == 0) ? dis[grow] : 1.0f;
            #pragma unroll
            for (int nt = 0; nt < 4; ++nt) {
                float v = fmaxf(acc[mt][nt][r] + bv[nt], 0.f);
                if (MODE == 0) v *= dv;
                smem[lrow * CLD + wn + nt * 16 + l16] = f2bf(v);
            }
        }
    }
    __syncthreads();
    // phase 2: LDS -> global, 16B coalesced chunks (2048 chunks, 8 per thread)
    for (int c = tid; c < 2048; c += 256) {
        int lrow = c >> 4, coff = (c & 15) << 3;
        int grow = bm + lrow;
        if (grow < M)
            *(u16x8*)(Cout + (size_t)grow * HID + bn + coff) = *(const u16x8*)&smem[lrow * CLD + coff];
    }
}
#undef CLD

// layer-1 aggregation over Xs (bf16, 128 feat, 4B/lane): Xa[v] = bf16(dis[v]*(Σ_N Xs[u] + Xs[v]))
__global__ __launch_bounds__(256) void agg128_kernel(
        const unsigned short* __restrict__ Xs, const int* __restrict__ row_ptr,
        const int* __restrict__ col, const float* __restrict__ dis,
        unsigned short* __restrict__ Xa, int n) {
    int node = blockIdx.x * 4 + (threadIdx.x >> 6);
    if (node >= n) return;
    int lane = threadIdx.x & 63;
    const unsigned int* Xv = (const unsigned int*)Xs;
    unsigned int p = Xv[(size_t)node * 64 + lane];  // self loop
    float ax = bflo(p), ay = bfhi(p);
    int e = row_ptr[node], end = row_ptr[node + 1];
    for (; e + 7 < end; e += 8) {
        unsigned int m[8];
        #pragma unroll
        for (int j = 0; j < 8; ++j) m[j] = Xv[(size_t)col[e + j] * 64 + lane];
        #pragma unroll
        for (int j = 0; j < 8; ++j) { ax += bflo(m[j]); ay += bfhi(m[j]); }
    }
    for (; e < end; ++e) {
        unsigned int m = Xv[(size_t)col[e] * 64 + lane];
        ax += bflo(m); ay += bfhi(m);
    }
    float dv = dis[node];
    unsigned int o = (unsigned int)f2bf(dv * ax) | ((unsigned int)f2bf(dv * ay) << 16);
    ((unsigned int*)Xa)[(size_t)node * 64 + lane] = o;
}

// layers 2,3 aggregation over Hs (bf16, 256 feat, 8B/lane): G[v] = bf16(dis[v]*(Σ_N Hs[u] + Hs[v]))
__global__ __launch_bounds__(256) void agg256_kernel(
        const unsigned short* __restrict__ Hs, const int* __restrict__ row_ptr,
        const int* __restrict__ col, const float* __restrict__ dis,
        unsigned short* __restrict__ G, int n) {
    int node = blockIdx.x * 4 + (threadIdx.x >> 6);
    if (node >= n) return;
    int lane = threadIdx.x & 63;
    const uint2* Hv = (const uint2*)Hs;
    uint2 p = Hv[(size_t)node * 64 + lane];
    float4 acc = make_float4(bflo(p.x), bfhi(p.x), bflo(p.y), bfhi(p.y));
    int e = row_ptr[node], end = row_ptr[node + 1];
    for (; e + 7 < end; e += 8) {
        uint2 m[8];
        #pragma unroll
        for (int j = 0; j < 8; ++j) m[j] = Hv[(size_t)col[e + j] * 64 + lane];
        #pragma unroll
        for (int j = 0; j < 8; ++j) {
            acc.x += bflo(m[j].x); acc.y += bfhi(m[j].x);
            acc.z += bflo(m[j].y); acc.w += bfhi(m[j].y);
        }
    }
    for (; e < end; ++e) {
        uint2 m = Hv[(size_t)col[e] * 64 + lane];
        acc.x += bflo(m.x); acc.y += bfhi(m.x);
        acc.z += bflo(m.y); acc.w += bfhi(m.y);
    }
    float dv = dis[node];
    ushort4 o;
    o.x = f2bf(dv * acc.x); o.y = f2bf(dv * acc.y);
    o.z = f2bf(dv * acc.z); o.w = f2bf(dv * acc.w);
    ((ushort4*)G)[(size_t)node * 64 + lane] = o;
}

// one block per graph: mean-pool (bf16 Hf) + concat + FC1(relu) + FC2
__global__ __launch_bounds__(256) void pool_mlp_kernel(
        const unsigned short* __restrict__ H, const int* __restrict__ goff,
        const float* __restrict__ mol, const float* __restrict__ rings,
        const float* __restrict__ fcW1, const float* __restrict__ fcb1,
        const float* __restrict__ fcW2, const float* __restrict__ fcb2,
        float* __restrict__ out) {
    __shared__ float s_hg[258];
    __shared__ float s_t[196];
    int g = blockIdx.x, tid = threadIdx.x;
    int beg = goff[g], end = goff[g + 1];
    float acc = 0.f;
    for (int i = beg; i < end; ++i) acc += bf2f(H[(size_t)i * HID + tid]);
    s_hg[tid] = acc / fmaxf((float)(end - beg), 1.0f);
    if (tid == 0) { s_hg[256] = mol[g]; s_hg[257] = rings[g]; }
    __syncthreads();
    if (tid < 196) {
        float a = fcb1[tid];
        for (int k = 0; k < 258; ++k) a = fmaf(s_hg[k], fcW1[k * 196 + tid], a);
        s_t[tid] = fmaxf(a, 0.f);
    }
    __syncthreads();
    if (tid < 16) {
        float a = fcb2[tid];
        for (int k = 0; k < 196; ++k) a = fmaf(s_t[k], fcW2[k * 16 + tid], a);
        out[g * 16 + tid] = a;
    }
}

extern "C" void kernel_launch(void* const* d_in, const int* in_sizes, int n_in,
                              void* d_out, int out_size, void* d_ws, size_t ws_size,
                              hipStream_t stream) {
    const float* x     = (const float*)d_in[0];
    const int*   ei    = (const int*)d_in[1];
    const int*   batch = (const int*)d_in[2];
    const float* mol   = (const float*)d_in[3];
    const float* rings = (const float*)d_in[4];
    const float* W1 = (const float*)d_in[5];
    const float* b1 = (const float*)d_in[6];
    const float* W2 = (const float*)d_in[7];
    const float* b2 = (const float*)d_in[8];
    const float* W3 = (const float*)d_in[9];
    const float* b3 = (const float*)d_in[10];
    const float* fcW1 = (const float*)d_in[11];
    const float* fcb1 = (const float*)d_in[12];
    const float* fcW2 = (const float*)d_in[13];
    const float* fcb2 = (const float*)d_in[14];
    float* out = (float*)d_out;
    const int* src = ei;
    const int* dst = ei + NE;

    char* w = (char*)d_ws;
    auto alloc = [&](size_t bytes) {
        char* p = w;
        w += (bytes + 255) & ~(size_t)255;
        return p;
    };
    int*   gbuk    = (int*)alloc((size_t)NBUK * 4);
    int*   bukoff  = (int*)alloc((size_t)(NBUK + 1) * 4);
    int*   bukcur  = (int*)alloc((size_t)NBUK * 4);
    int*   row_ptr = (int*)alloc((size_t)(NN + 1) * 4);
    int*   goff    = (int*)alloc((size_t)(NG + 1) * 4);
    float* dis     = (float*)alloc((size_t)NN * 4);
    unsigned int* pairs = (unsigned int*)alloc((size_t)NE * 4);
    int*   col     = (int*)alloc((size_t)NE * 4);
    unsigned short* Xs  = (unsigned short*)alloc((size_t)NN * FIN * 2);
    unsigned short* Xa  = (unsigned short*)alloc((size_t)NN * FIN * 2);
    unsigned short* Hs  = (unsigned short*)alloc((size_t)NN * HID * 2);
    unsigned short* Ga  = (unsigned short*)alloc((size_t)NN * HID * 2);
    unsigned short* Hf  = (unsigned short*)alloc((size_t)NN * HID * 2);
    unsigned short* W1t = (unsigned short*)alloc((size_t)FIN * HID * 2);
    unsigned short* W2t = (unsigned short*)alloc((size_t)HID * HID * 2);
    unsigned short* W3t = (unsigned short*)alloc((size_t)HID * HID * 2);

    hipMemsetAsync(gbuk, 0, (size_t)NBUK * 4, stream);
    int eb = cdiv(NE, 2048);  // 391
    hist_bucket_kernel<<<eb, 256, 0, stream>>>(dst, gbuk);
    goff_kernel<<<cdiv(NN, 256), 256, 0, stream>>>(batch, goff);
    buk_scan_kernel<<<1, 256, 0, stream>>>(gbuk, bukoff, bukcur);
    scatter_kernel<<<eb, 256, 0, stream>>>(src, dst, bukcur, pairs);
    local_csr_kernel<<<NBUK, 256, 0, stream>>>(pairs, bukoff, row_ptr, col, dis);

    cast_scale_kernel<<<cdiv(NN * FIN / 4, 256), 256, 0, stream>>>(x, dis, Xs, NN * FIN / 4);
    tcast_all_kernel<<<cdiv((FIN + HID + HID) * 256, 256), 256, 0, stream>>>(W1, W2, W3, W1t, W2t, W3t);

    dim3 ggrid(cdiv(NN, 128), 2);
    int agrid = cdiv(NN, 4);
    // all layers: aggregate-then-transform (aggregation commutes with @W)
    agg128_kernel<<<agrid, 256, 0, stream>>>(Xs, row_ptr, col, dis, Xa, NN);
    gemm128_kernel<0><<<ggrid, 256, 0, stream>>>(Xa, W1t, dis, b1, Hs, NN, FIN);  // Hs1 = bf16(dis*relu)
    agg256_kernel<<<agrid, 256, 0, stream>>>(Hs, row_ptr, col, dis, Ga, NN);       // Ga2
    gemm128_kernel<0><<<ggrid, 256, 0, stream>>>(Ga, W2t, dis, b2, Hs, NN, HID);  // Hs2
    agg256_kernel<<<agrid, 256, 0, stream>>>(Hs, row_ptr, col, dis, Ga, NN);       // Ga3
    gemm128_kernel<1><<<ggrid, 256, 0, stream>>>(Ga, W3t, dis, b3, Hf, NN, HID);  // Hf = bf16(relu)
    pool_mlp_kernel<<<NG, 256, 0, stream>>>(Hf, goff, mol, rings, fcW1, fcb1, fcW2, fcb2, out);
}